// Round 9
// baseline (1206.988 us; speedup 1.0000x reference)
//
#include <hip/hip_runtime.h>
#include <hip/hip_bf16.h>
#include <stdint.h>

// ---------------------------------------------------------------------------
// Problem geometry
//   x (4,400,128) -> conv1d(200->512,k3,p1,relu) -> conv1d(512->128,k3,p1,relu) = h
//   x4 = sigmoid(0.01*conv1d(h, w3(3,128,1))) -> outputs xc(ch2), xb_start(ch0), xb_end(ch1)
//   cm = einsum('bct,tm->bcm', h, mask) ; conv3d(w3d, stride 32) + b3d, relu
//     == relu(b3d[o] + sum_{s,t} mask[t,s,i,j] * H2[b,o,s,t]),
//        H2[b,o,s,t] = sum_c w3d[o,c,s] * h[b,c,t]      (mask: <=6 taps per (s,i,j))
//   then 1x1(512->128,relu), 3x3(128->64,relu), 3x3(64->64,relu), 1x1(64->4,sigmoid)
//   outputs (float32): xc,xb_start,xb_end (3*512) | iou (4,2,128,128) | prop_start | prop_end
//
// cm stored TRANSPOSED: cm2[ij][bo]. k_bm (round-7 proven config): 128-thr
// blocks, thread owns bo-pair (dword = 2 bf16/tap), taps broadcast from LDS,
// grid (x=boT 8 -> XCD-pinned 2MB h2t slice, y = i*4 + quarter).
// conva / conv3x3 split by output channels (gridDim.z=2) for 4 blocks/CU.
// ---------------------------------------------------------------------------

typedef unsigned int uint32;

__device__ __forceinline__ float bf2f(ushort u) {
    return __uint_as_float(((uint32)u) << 16);
}
__device__ __forceinline__ ushort f2bf(float f) {
    uint32 x = __float_as_uint(f);
    uint32 r = (x + 0x7FFFu + ((x >> 16) & 1u)) >> 16;
    return (ushort)r;
}
__device__ __forceinline__ float sigmoidf(float x) {
    return 1.0f / (1.0f + __expf(-x));
}

// ---------------------------------------------------------------------------
// conv1d (k=3, pad=1, relu). Block: 16 out-channels x 128 t. Grid (COUT/16, B).
// ---------------------------------------------------------------------------
__global__ __launch_bounds__(256) void k_conv1d_relu(
    const float* __restrict__ in, const float* __restrict__ w,
    const float* __restrict__ bias, float* __restrict__ out,
    int CIN, int in_batch_stride, int COUT)
{
    __shared__ float lx[64 * 132];   // [c][0..127 data, 128 = zero pad]
    int b  = blockIdx.y;
    int o  = blockIdx.x * 16 + (threadIdx.x >> 4);
    int tg = threadIdx.x & 15;
    int t0 = tg * 8;

    float acc[8];
#pragma unroll
    for (int k = 0; k < 8; ++k) acc[k] = 0.0f;

    for (int c0 = 0; c0 < CIN; c0 += 64) {
        int nc = CIN - c0; if (nc > 64) nc = 64;
        __syncthreads();
        for (int n = threadIdx.x; n < nc * 32; n += 256) {
            int cl = n >> 5, q = n & 31;
            float4 v = *(const float4*)(in + ((size_t)(b * in_batch_stride + c0 + cl)) * 128 + q * 4);
            *(float4*)(&lx[cl * 132 + q * 4]) = v;
        }
        for (int cl = threadIdx.x; cl < nc; cl += 256) lx[cl * 132 + 128] = 0.0f;
        __syncthreads();

        for (int cl = 0; cl < nc; ++cl) {
            int c = c0 + cl;
            const float* wp = w + ((size_t)o * CIN + c) * 3;
            float w0 = wp[0], w1 = wp[1], w2 = wp[2];
            const float* row = &lx[cl * 132];
            float xv[10];
            if (t0 == 0) {
                xv[0] = 0.0f;
#pragma unroll
                for (int k = 1; k < 10; ++k) xv[k] = row[k - 1];
            } else {
#pragma unroll
                for (int k = 0; k < 10; ++k) xv[k] = row[t0 - 1 + k];
            }
#pragma unroll
            for (int k = 0; k < 8; ++k)
                acc[k] += w0 * xv[k] + w1 * xv[k + 1] + w2 * xv[k + 2];
        }
    }
    float bo = bias[o];
#pragma unroll
    for (int k = 0; k < 8; ++k) {
        float v = acc[k] + bo;
        out[((size_t)(b * COUT + o)) * 128 + t0 + k] = v > 0.0f ? v : 0.0f;
    }
}

// ---------------------------------------------------------------------------
// x4 head -> d_out[0:1536] floats: (xc=ch2 | xb_start=ch0 | xb_end=ch1)
// ---------------------------------------------------------------------------
__global__ void k_x4(const float* __restrict__ h, const float* __restrict__ w3,
                     const float* __restrict__ b3, float* __restrict__ outp)
{
    int tid = threadIdx.x;
    int b = tid >> 7, t = tid & 127;
    float a0 = 0.f, a1 = 0.f, a2 = 0.f;
    for (int c = 0; c < 128; ++c) {
        float hv = h[((size_t)(b * 128 + c)) * 128 + t];
        a0 += w3[c] * hv;
        a1 += w3[128 + c] * hv;
        a2 += w3[256 + c] * hv;
    }
    float s0 = sigmoidf(0.01f * (a0 + b3[0]));
    float s1 = sigmoidf(0.01f * (a1 + b3[1]));
    float s2 = sigmoidf(0.01f * (a2 + b3[2]));
    int bt = b * 128 + t;
    outp[bt]        = s2;   // xc
    outp[512 + bt]  = s0;   // xb_start
    outp[1024 + bt] = s1;   // xb_end
}

// ---------------------------------------------------------------------------
// H2t[(s*128+t)*2048 + b*512+o] = bf16( sum_c w3d[o,c,s]*h[b,c,t] )
// ---------------------------------------------------------------------------
__global__ __launch_bounds__(256) void k_h2(
    const float* __restrict__ h, const float* __restrict__ w3d,
    ushort* __restrict__ h2t)
{
    __shared__ float lw[64 * 129];     // [o][c]
    __shared__ float lhs[32 * 132];    // [c_local][t] ; reused as ushort out stage
    int ot = blockIdx.x, s = blockIdx.y, b = blockIdx.z;
    int o0 = ot * 64;

    for (int n = threadIdx.x; n < 8192; n += 256) {
        int o = n >> 7, c = n & 127;
        lw[o * 129 + c] = w3d[(size_t)(o0 + o) * 4096 + c * 32 + s];
    }

    int og = threadIdx.x >> 4, tg = threadIdx.x & 15;
    int o0t = og * 4, t0 = tg * 8;
    float acc[4][8];
#pragma unroll
    for (int oo = 0; oo < 4; ++oo)
#pragma unroll
        for (int k = 0; k < 8; ++k) acc[oo][k] = 0.0f;

    for (int c0 = 0; c0 < 128; c0 += 32) {
        __syncthreads();
        for (int n = threadIdx.x; n < 1024; n += 256) {
            int cl = n >> 5, q = n & 31;
            *(float4*)(&lhs[cl * 132 + q * 4]) =
                *(const float4*)(h + ((size_t)(b * 128 + c0 + cl)) * 128 + q * 4);
        }
        __syncthreads();
        for (int cl = 0; cl < 32; ++cl) {
            float hv[8];
#pragma unroll
            for (int k = 0; k < 8; ++k) hv[k] = lhs[cl * 132 + t0 + k];
#pragma unroll
            for (int oo = 0; oo < 4; ++oo) {
                float wv = lw[(o0t + oo) * 129 + c0 + cl];
#pragma unroll
                for (int k = 0; k < 8; ++k) acc[oo][k] += wv * hv[k];
            }
        }
    }
    __syncthreads();
    ushort* lout = (ushort*)lhs;       // [t*64 + o]
#pragma unroll
    for (int oo = 0; oo < 4; ++oo)
#pragma unroll
        for (int k = 0; k < 8; ++k)
            lout[(t0 + k) * 64 + o0t + oo] = f2bf(acc[oo][k]);
    __syncthreads();
    for (int n = threadIdx.x; n < 8192; n += 256) {
        int t = n >> 6, o = n & 63;
        h2t[(size_t)(s * 128 + t) * 2048 + b * 512 + o0 + o] = lout[n];
    }
}

// ---------------------------------------------------------------------------
// E1: per mask column m=(s,i,j), collect nonzero (t,w) taps (<=6 exist, cap 8).
// ---------------------------------------------------------------------------
__global__ __launch_bounds__(256) void k_e1(
    const float* __restrict__ mask, uint32* __restrict__ ecnt,
    uint8_t* __restrict__ et, float* __restrict__ ew)
{
    uint32 m = blockIdx.x * 256 + threadIdx.x;
    int cnt = 0;
    for (int t = 0; t < 128; ++t) {
        float w = mask[(size_t)t * 524288 + m];
        if (w != 0.0f) {
            if (cnt < 8) {
                et[(size_t)m * 8 + cnt] = (uint8_t)t;
                ew[(size_t)m * 8 + cnt] = w;
            }
            cnt++;
        }
    }
    ecnt[m] = (uint32)(cnt < 8 ? cnt : 8);
}

// ---------------------------------------------------------------------------
// E2: merge per (i,j): taps over all 32 s -> packed {w_bits, byte_off} (<=192).
// byte_off = st * 4096 (h2t row pitch in bytes) so k_bm's inner loop is lean.
// ---------------------------------------------------------------------------
__global__ void k_e2(const uint32* __restrict__ ecnt, const uint8_t* __restrict__ et,
                     const float* __restrict__ ew, uint32* __restrict__ cntij,
                     int2* __restrict__ taps)
{
    int lane = threadIdx.x & 31;
    int col = blockIdx.x * 2 + (threadIdx.x >> 5);
    uint32 m = (uint32)lane * 16384u + (uint32)col;
    int c = (int)ecnt[m];
    int v = c;
    for (int d = 1; d < 32; d <<= 1) {
        int t = __shfl_up(v, d, 32);
        if (lane >= d) v += t;
    }
    int off = v - c;
    if (lane == 31) cntij[col] = (uint32)v;
    for (int k = 0; k < c; ++k) {
        int2 r;
        r.x = __float_as_int(ew[(size_t)m * 8 + k]);
        r.y = ((lane << 7) + (int)et[(size_t)m * 8 + k]) << 12;   // st * 4096 bytes
        taps[(size_t)col * 192 + off + k] = r;
    }
}

// ---------------------------------------------------------------------------
// k_wt: transpose conv3x3 weights (COUT=64, CIN, 3, 3) -> wT[(cin*9+kk)*64+cout]
// ---------------------------------------------------------------------------
__global__ __launch_bounds__(256) void k_wt(
    const float* __restrict__ w, float* __restrict__ wT, int CIN)
{
    int n = blockIdx.x * 256 + threadIdx.x;
    int total = 64 * CIN * 9;
    if (n >= total) return;
    int per = CIN * 9;
    int cout = n / per;
    int rem = n - cout * per;     // cin*9 + kk
    wT[(size_t)rem * 64 + cout] = w[n];
}

// ---------------------------------------------------------------------------
// k_bm (round-7 proven config): cm2[ij, bo] = relu(b3d[o] + sum w*H2t[st,bo])
// Thread owns bo-pair (2*tid, 2*tid+1): one dword load per tap = 2 bf16 = 2
// MACs, 2 independent FMA chains. Grid (x=boT 8, y = i*4 + quarter): x fastest
// pins each 2MB h2t bo-slice to one XCD's L2. 4096 blocks x 128 thr.
// ---------------------------------------------------------------------------
__global__ __launch_bounds__(128) void k_bm(
    const ushort* __restrict__ h2t, const int2* __restrict__ taps,
    const uint32* __restrict__ cntij, const float* __restrict__ b3d,
    ushort* __restrict__ cm2)
{
    __shared__ int2 tl[8 * 192];        // 12,288 B
    int boT = blockIdx.x;
    int i = blockIdx.y >> 2, q = blockIdx.y & 3;
    int tid = threadIdx.x;
    int bo0 = boT * 256 + tid * 2;
    const char* hb = (const char*)h2t + (size_t)bo0 * 2;
    float bias0 = b3d[bo0 & 511];
    float bias1 = b3d[(bo0 & 511) + 1];
    uint32* cm32 = (uint32*)cm2;

    for (int jc = 0; jc < 4; ++jc) {
        int j0 = q * 32 + jc * 8;
        int ij0 = i * 128 + j0;
        int cnts[8];
#pragma unroll
        for (int c = 0; c < 8; ++c) cnts[c] = (int)cntij[ij0 + c];
        __syncthreads();   // previous chunk's readers done before tl overwrite
        for (int n = tid; n < 1536; n += 128) {
            int c = n / 192, k = n - c * 192;
            if (k < cnts[c]) tl[n] = taps[(size_t)(ij0 + c) * 192 + k];
        }
        __syncthreads();
#pragma unroll 1
        for (int c = 0; c < 8; ++c) {
            int cnt = cnts[c];
            const int2* tp = &tl[c * 192];
            float a0 = 0.0f, a1 = 0.0f;
#pragma unroll 16
            for (int k = 0; k < cnt; ++k) {
                int2 r = tp[k];
                uint32 hv = *(const uint32*)(hb + (uint32)r.y);
                float w = __int_as_float(r.x);
                a0 += w * __uint_as_float(hv << 16);
                a1 += w * __uint_as_float(hv & 0xffff0000u);
            }
            float v0 = a0 + bias0; v0 = v0 > 0.0f ? v0 : 0.0f;
            float v1 = a1 + bias1; v1 = v1 > 0.0f ? v1 : 0.0f;
            uint32 pr = (uint32)f2bf(v0) | ((uint32)f2bf(v1) << 16);
            __builtin_nontemporal_store(pr, &cm32[((size_t)(ij0 + c) * 2048 + bo0) >> 1]);
        }
    }
}

// ---------------------------------------------------------------------------
// conv-a: 1x1, 512 -> 128, relu.  Reads cm2[ij][bo]. Split: z = c-half (64 c).
// p1[b,c,ij] = relu(ba[c] + sum_o wa[c,o]*cm2[ij, b*512+o])
// ---------------------------------------------------------------------------
__global__ __launch_bounds__(256) void k_conva(
    const ushort* __restrict__ cm2, const float* __restrict__ wa,
    const float* __restrict__ ba, float* __restrict__ p1)
{
    __shared__ float lx[32 * 132];   // [oo][j]      16,896 B
    __shared__ float lwv[32 * 68];   // [oo][c_loc]   8,704 B
    int i = blockIdx.x, b = blockIdx.y, z = blockIdx.z;
    int cg = threadIdx.x >> 4, jg = threadIdx.x & 15;
    int c0l = cg * 4, j0 = jg * 8;   // c_global = z*64 + c0l + cc
    float acc[4][8];
#pragma unroll
    for (int cc = 0; cc < 4; ++cc)
#pragma unroll
        for (int k = 0; k < 8; ++k) acc[cc][k] = 0.0f;

    for (int o0 = 0; o0 < 512; o0 += 32) {
        __syncthreads();
        // stage 128 j x 32 o from cm2[(i*128+j)*2048 + b*512 + o0 + *]
        for (int n = threadIdx.x; n < 2048; n += 256) {
            int j = n >> 4, q = n & 15;            // q = o-pair index
            uint32 v = *(const uint32*)(cm2 + ((size_t)(i * 128 + j)) * 2048 + b * 512 + o0 + 2 * q);
            lx[(2 * q) * 132 + j]     = bf2f((ushort)(v & 0xffffu));
            lx[(2 * q + 1) * 132 + j] = bf2f((ushort)(v >> 16));
        }
        // stage weights for this c-half: 64 c x 32 o
        for (int n = threadIdx.x; n < 2048; n += 256) {
            int oo = n & 31, c = n >> 5;           // c in [0,64)
            lwv[oo * 68 + c] = wa[(size_t)(z * 64 + c) * 512 + o0 + oo];
        }
        __syncthreads();
        for (int oo = 0; oo < 32; ++oo) {
            float xv[8], wvv[4];
#pragma unroll
            for (int k = 0; k < 8; ++k) xv[k] = lx[oo * 132 + j0 + k];
#pragma unroll
            for (int cc = 0; cc < 4; ++cc) wvv[cc] = lwv[oo * 68 + c0l + cc];
#pragma unroll
            for (int cc = 0; cc < 4; ++cc)
#pragma unroll
                for (int k = 0; k < 8; ++k) acc[cc][k] += wvv[cc] * xv[k];
        }
    }
#pragma unroll
    for (int cc = 0; cc < 4; ++cc) {
        int cglob = z * 64 + c0l + cc;
        float bb = ba[cglob];
#pragma unroll
        for (int k = 0; k < 8; ++k) {
            float v = acc[cc][k] + bb;
            v = v > 0.0f ? v : 0.0f;
            p1[((size_t)(b * 128 + cglob)) * 16384 + i * 128 + j0 + k] = v;
        }
    }
}

// ---------------------------------------------------------------------------
// 3x3 conv, CIN -> 64, pad 1, relu. Split: z = cout-half (32 couts/block).
// Weights from pre-transposed wT ([cin][kk][cout]); div-free staging.
// ---------------------------------------------------------------------------
template <int CIN>
__global__ __launch_bounds__(256) void k_conv3x3(
    const float* __restrict__ in, const float* __restrict__ wT,
    const float* __restrict__ bias, float* __restrict__ out)
{
    __shared__ float lx[8][3 * 132];   // 8 ch x 3 rows, padded   12,672 B
    __shared__ float lwsf[2304];       // [ch*9 + kk][32 couts]    9,216 B
    int i = blockIdx.x, b = blockIdx.y, z = blockIdx.z;
    int cg = threadIdx.x >> 4, jg = threadIdx.x & 15;
    int c0l = cg * 2, j0 = jg * 8;     // cout_global = z*32 + c0l + cc
    int sch = threadIdx.x >> 5, sl = threadIdx.x & 31;
    float acc[2][8];
#pragma unroll
    for (int cc = 0; cc < 2; ++cc)
#pragma unroll
        for (int k = 0; k < 8; ++k) acc[cc][k] = 0.0f;

    for (int o0 = 0; o0 < CIN; o0 += 8) {
        __syncthreads();
        {
            const float* src = in + (size_t)(b * CIN + o0 + sch) * 16384;
#pragma unroll
            for (int r = 0; r < 3; ++r) {
                int ii = i + r - 1;
                bool rowok = (ii >= 0) && (ii < 128);
#pragma unroll
                for (int p = 0; p < 5; ++p) {
                    int col = p * 32 + sl;
                    if (col < 130) {
                        int jj = col - 1;
                        float v = 0.0f;
                        if (rowok && jj >= 0 && jj < 128)
                            v = src[ii * 128 + jj];
                        lx[sch][r * 132 + col] = v;
                    }
                }
            }
        }
        {
            const float* wsrc = wT + (size_t)o0 * 576 + z * 32;  // rows of 64, take 32
            for (int n = threadIdx.x; n < 2304; n += 256) {
                int row = n >> 5, cl = n & 31;
                lwsf[n] = wsrc[row * 64 + cl];
            }
        }
        __syncthreads();

#pragma unroll 1
        for (int ch = 0; ch < 8; ++ch) {
            float x0[10], x1[10], x2[10];
#pragma unroll
            for (int k = 0; k < 10; ++k) {
                x0[k] = lx[ch][0 * 132 + j0 + k];
                x1[k] = lx[ch][1 * 132 + j0 + k];
                x2[k] = lx[ch][2 * 132 + j0 + k];
            }
#pragma unroll
            for (int cc = 0; cc < 2; ++cc) {
                const float* wp = &lwsf[ch * 288 + c0l + cc];
                float w00 = wp[0],   w01 = wp[32],  w02 = wp[64];
                float w10 = wp[96],  w11 = wp[128], w12 = wp[160];
                float w20 = wp[192], w21 = wp[224], w22 = wp[256];
#pragma unroll
                for (int k = 0; k < 8; ++k) {
                    acc[cc][k] += w00 * x0[k] + w01 * x0[k + 1] + w02 * x0[k + 2]
                                + w10 * x1[k] + w11 * x1[k + 1] + w12 * x1[k + 2]
                                + w20 * x2[k] + w21 * x2[k + 1] + w22 * x2[k + 2];
                }
            }
        }
    }
#pragma unroll
    for (int cc = 0; cc < 2; ++cc) {
        int cglob = z * 32 + c0l + cc;
        float bb = bias[cglob];
#pragma unroll
        for (int k = 0; k < 8; ++k) {
            float v = acc[cc][k] + bb;
            v = v > 0.0f ? v : 0.0f;
            out[((size_t)(b * 64 + cglob) * 128 + i) * 128 + j0 + k] = v;
        }
    }
}

// ---------------------------------------------------------------------------
// conv-d: 1x1, 64 -> 4, sigmoid, scatter to d_out floats
// ---------------------------------------------------------------------------
__global__ __launch_bounds__(256) void k_convd(
    const float* __restrict__ p3, const float* __restrict__ wd,
    const float* __restrict__ bd, float* __restrict__ outp)
{
    __shared__ float lw[256];
    int b = blockIdx.y;
    int ij = blockIdx.x * 256 + threadIdx.x;
    lw[threadIdx.x] = wd[threadIdx.x];
    __syncthreads();
    float a0 = bd[0], a1 = bd[1], a2 = bd[2], a3 = bd[3];
    for (int c = 0; c < 64; ++c) {
        float v = p3[((size_t)(b * 64 + c)) * 16384 + ij];
        a0 += lw[c] * v;
        a1 += lw[64 + c] * v;
        a2 += lw[128 + c] * v;
        a3 += lw[192 + c] * v;
    }
    outp[1536 + (size_t)(b * 2 + 0) * 16384 + ij] = sigmoidf(a2);  // iou ch0
    outp[1536 + (size_t)(b * 2 + 1) * 16384 + ij] = sigmoidf(a3);  // iou ch1
    outp[132608 + (size_t)b * 16384 + ij] = sigmoidf(a0);          // prop_start
    outp[198144 + (size_t)b * 16384 + ij] = sigmoidf(a1);          // prop_end
}

// ---------------------------------------------------------------------------
extern "C" void kernel_launch(void* const* d_in, const int* in_sizes, int n_in,
                              void* d_out, int out_size, void* d_ws, size_t ws_size,
                              hipStream_t stream)
{
    const float* x   = (const float*)d_in[0];
    const float* w1  = (const float*)d_in[1];
    const float* b1  = (const float*)d_in[2];
    const float* w2  = (const float*)d_in[3];
    const float* b2  = (const float*)d_in[4];
    const float* w3  = (const float*)d_in[5];
    const float* b3  = (const float*)d_in[6];
    const float* w3d = (const float*)d_in[7];
    const float* b3d = (const float*)d_in[8];
    const float* wa  = (const float*)d_in[9];
    const float* ba  = (const float*)d_in[10];
    const float* wb  = (const float*)d_in[11];
    const float* bb  = (const float*)d_in[12];
    const float* wc  = (const float*)d_in[13];
    const float* bc  = (const float*)d_in[14];
    const float* wd  = (const float*)d_in[15];
    const float* bd  = (const float*)d_in[16];
    const float* sm  = (const float*)d_in[17];
    float* outp = (float*)d_out;
    char* ws = (char*)d_ws;

    // workspace layout (with aliasing; peak ~127.3 MB)
    float*  h1    = (float*)(ws + 0);              //  1,048,576 B
    float*  h     = (float*)(ws + 1048576);        //    262,144 B
    ushort* h2t   = (ushort*)(ws + 1310720);       // 16,777,216 B
    uint32* ecnt  = (uint32*)(ws + 18087936);      //  2,097,152 B
    uint8_t* et   = (uint8_t*)(ws + 20185088);     //  4,194,304 B
    float*  ewf   = (float*)(ws + 24379392);       // 16,777,216 B (dead after e2)
    uint32* cntij = (uint32*)(ws + 41156608);      //     65,536 B
    int2*   taps  = (int2*)(ws + 41222144);        // 25,165,824 B
    ushort* cm2   = (ushort*)(ws + 66387968);      // 67,108,864 B  [ij][bo]
    float*  p1    = (float*)(ws + 1310720);        // 33,554,432 B (aliases h2t+e-bufs)
    float*  p2    = (float*)(ws + 41222144);       // 16,777,216 B (aliases taps)
    float*  p3    = (float*)(ws + 66387968);       // 16,777,216 B (aliases cm2)
    float*  wbT   = (float*)(ws + 34865152);       //    294,912 B (in dead ewf zone, > p1 end)
    float*  wcT   = (float*)(ws + 35160064);       //    147,456 B (ends < cntij)

    dim3 blk(256);
    k_conv1d_relu<<<dim3(32, 4), blk, 0, stream>>>(x, w1, b1, h1, 200, 400, 512);
    k_conv1d_relu<<<dim3(8, 4), blk, 0, stream>>>(h1, w2, b2, h, 512, 512, 128);
    k_x4<<<1, 512, 0, stream>>>(h, w3, b3, outp);
    k_h2<<<dim3(8, 32, 4), blk, 0, stream>>>(h, w3d, h2t);
    k_e1<<<2048, blk, 0, stream>>>(sm, ecnt, et, ewf);
    k_e2<<<8192, 64, 0, stream>>>(ecnt, et, ewf, cntij, taps);
    k_wt<<<288, blk, 0, stream>>>(wb, wbT, 128);
    k_wt<<<144, blk, 0, stream>>>(wc, wcT, 64);
    k_bm<<<dim3(8, 512), dim3(128), 0, stream>>>(h2t, taps, cntij, b3d, cm2);
    k_conva<<<dim3(128, 4, 2), blk, 0, stream>>>(cm2, wa, ba, p1);
    k_conv3x3<128><<<dim3(128, 4, 2), blk, 0, stream>>>(p1, wbT, bb, p2);
    k_conv3x3<64><<<dim3(128, 4, 2), blk, 0, stream>>>(p2, wcT, bc, p3);
    k_convd<<<dim3(64, 4), blk, 0, stream>>>(p3, wd, bd, outp);
}

// Round 10
// 1009.791 us; speedup vs baseline: 1.1953x; 1.1953x over previous
//
#include <hip/hip_runtime.h>
#include <hip/hip_bf16.h>
#include <stdint.h>

// ---------------------------------------------------------------------------
// Problem geometry
//   x (4,400,128) -> conv1d(200->512,k3,p1,relu) -> conv1d(512->128,k3,p1,relu) = h
//   x4 = sigmoid(0.01*conv1d(h, w3(3,128,1))) -> outputs xc(ch2), xb_start(ch0), xb_end(ch1)
//   cm = einsum('bct,tm->bcm', h, mask) ; conv3d(w3d, stride 32) + b3d, relu
//     == relu(b3d[o] + sum_{s,t} mask[t,s,i,j] * H2[b,o,s,t])   (<=6 taps/(s,i,j))
//   then 1x1(512->128,relu) [MFMA], 3x3(128->64,relu), 3x3(64->64,relu),
//   1x1(64->4,sigmoid)
//   outputs (float32): xc,xb_start,xb_end (3*512) | iou (4,2,128,128) | prop_start | prop_end
//
// cm stored TRANSPOSED: cm2[ij][bo]. k_bm (round-7 proven config): 128-thr
// blocks, thread owns bo-pair, taps broadcast from LDS, grid (x=boT 8 ->
// XCD-pinned 2MB h2t slice, y = i*4 + quarter).
// conva = MFMA GEMM (16x16x32 bf16): D rows=c, cols=ij; K=o contiguous in cm2.
// ---------------------------------------------------------------------------

typedef unsigned int uint32;
typedef __attribute__((ext_vector_type(8))) short bf16x8;
typedef __attribute__((ext_vector_type(4))) float f32x4;

__device__ __forceinline__ float bf2f(ushort u) {
    return __uint_as_float(((uint32)u) << 16);
}
__device__ __forceinline__ ushort f2bf(float f) {
    uint32 x = __float_as_uint(f);
    uint32 r = (x + 0x7FFFu + ((x >> 16) & 1u)) >> 16;
    return (ushort)r;
}
__device__ __forceinline__ float sigmoidf(float x) {
    return 1.0f / (1.0f + __expf(-x));
}

// ---------------------------------------------------------------------------
// conv1d (k=3, pad=1, relu). Block: 16 out-channels x 128 t. Grid (COUT/16, B).
// ---------------------------------------------------------------------------
__global__ __launch_bounds__(256) void k_conv1d_relu(
    const float* __restrict__ in, const float* __restrict__ w,
    const float* __restrict__ bias, float* __restrict__ out,
    int CIN, int in_batch_stride, int COUT)
{
    __shared__ float lx[64 * 132];   // [c][0..127 data, 128 = zero pad]
    int b  = blockIdx.y;
    int o  = blockIdx.x * 16 + (threadIdx.x >> 4);
    int tg = threadIdx.x & 15;
    int t0 = tg * 8;

    float acc[8];
#pragma unroll
    for (int k = 0; k < 8; ++k) acc[k] = 0.0f;

    for (int c0 = 0; c0 < CIN; c0 += 64) {
        int nc = CIN - c0; if (nc > 64) nc = 64;
        __syncthreads();
        for (int n = threadIdx.x; n < nc * 32; n += 256) {
            int cl = n >> 5, q = n & 31;
            float4 v = *(const float4*)(in + ((size_t)(b * in_batch_stride + c0 + cl)) * 128 + q * 4);
            *(float4*)(&lx[cl * 132 + q * 4]) = v;
        }
        for (int cl = threadIdx.x; cl < nc; cl += 256) lx[cl * 132 + 128] = 0.0f;
        __syncthreads();

        for (int cl = 0; cl < nc; ++cl) {
            int c = c0 + cl;
            const float* wp = w + ((size_t)o * CIN + c) * 3;
            float w0 = wp[0], w1 = wp[1], w2 = wp[2];
            const float* row = &lx[cl * 132];
            float xv[10];
            if (t0 == 0) {
                xv[0] = 0.0f;
#pragma unroll
                for (int k = 1; k < 10; ++k) xv[k] = row[k - 1];
            } else {
#pragma unroll
                for (int k = 0; k < 10; ++k) xv[k] = row[t0 - 1 + k];
            }
#pragma unroll
            for (int k = 0; k < 8; ++k)
                acc[k] += w0 * xv[k] + w1 * xv[k + 1] + w2 * xv[k + 2];
        }
    }
    float bo = bias[o];
#pragma unroll
    for (int k = 0; k < 8; ++k) {
        float v = acc[k] + bo;
        out[((size_t)(b * COUT + o)) * 128 + t0 + k] = v > 0.0f ? v : 0.0f;
    }
}

// ---------------------------------------------------------------------------
// x4 head -> d_out[0:1536] floats: (xc=ch2 | xb_start=ch0 | xb_end=ch1)
// ---------------------------------------------------------------------------
__global__ void k_x4(const float* __restrict__ h, const float* __restrict__ w3,
                     const float* __restrict__ b3, float* __restrict__ outp)
{
    int tid = threadIdx.x;
    int b = tid >> 7, t = tid & 127;
    float a0 = 0.f, a1 = 0.f, a2 = 0.f;
    for (int c = 0; c < 128; ++c) {
        float hv = h[((size_t)(b * 128 + c)) * 128 + t];
        a0 += w3[c] * hv;
        a1 += w3[128 + c] * hv;
        a2 += w3[256 + c] * hv;
    }
    float s0 = sigmoidf(0.01f * (a0 + b3[0]));
    float s1 = sigmoidf(0.01f * (a1 + b3[1]));
    float s2 = sigmoidf(0.01f * (a2 + b3[2]));
    int bt = b * 128 + t;
    outp[bt]        = s2;   // xc
    outp[512 + bt]  = s0;   // xb_start
    outp[1024 + bt] = s1;   // xb_end
}

// ---------------------------------------------------------------------------
// H2t[(s*128+t)*2048 + b*512+o] = bf16( sum_c w3d[o,c,s]*h[b,c,t] )
// ---------------------------------------------------------------------------
__global__ __launch_bounds__(256) void k_h2(
    const float* __restrict__ h, const float* __restrict__ w3d,
    ushort* __restrict__ h2t)
{
    __shared__ float lw[64 * 129];     // [o][c]
    __shared__ float lhs[32 * 132];    // [c_local][t] ; reused as ushort out stage
    int ot = blockIdx.x, s = blockIdx.y, b = blockIdx.z;
    int o0 = ot * 64;

    for (int n = threadIdx.x; n < 8192; n += 256) {
        int o = n >> 7, c = n & 127;
        lw[o * 129 + c] = w3d[(size_t)(o0 + o) * 4096 + c * 32 + s];
    }

    int og = threadIdx.x >> 4, tg = threadIdx.x & 15;
    int o0t = og * 4, t0 = tg * 8;
    float acc[4][8];
#pragma unroll
    for (int oo = 0; oo < 4; ++oo)
#pragma unroll
        for (int k = 0; k < 8; ++k) acc[oo][k] = 0.0f;

    for (int c0 = 0; c0 < 128; c0 += 32) {
        __syncthreads();
        for (int n = threadIdx.x; n < 1024; n += 256) {
            int cl = n >> 5, q = n & 31;
            *(float4*)(&lhs[cl * 132 + q * 4]) =
                *(const float4*)(h + ((size_t)(b * 128 + c0 + cl)) * 128 + q * 4);
        }
        __syncthreads();
        for (int cl = 0; cl < 32; ++cl) {
            float hv[8];
#pragma unroll
            for (int k = 0; k < 8; ++k) hv[k] = lhs[cl * 132 + t0 + k];
#pragma unroll
            for (int oo = 0; oo < 4; ++oo) {
                float wv = lw[(o0t + oo) * 129 + c0 + cl];
#pragma unroll
                for (int k = 0; k < 8; ++k) acc[oo][k] += wv * hv[k];
            }
        }
    }
    __syncthreads();
    ushort* lout = (ushort*)lhs;       // [t*64 + o]
#pragma unroll
    for (int oo = 0; oo < 4; ++oo)
#pragma unroll
        for (int k = 0; k < 8; ++k)
            lout[(t0 + k) * 64 + o0t + oo] = f2bf(acc[oo][k]);
    __syncthreads();
    for (int n = threadIdx.x; n < 8192; n += 256) {
        int t = n >> 6, o = n & 63;
        h2t[(size_t)(s * 128 + t) * 2048 + b * 512 + o0 + o] = lout[n];
    }
}

// ---------------------------------------------------------------------------
// E1: per mask column m=(s,i,j), collect nonzero (t,w) taps (<=6 exist, cap 8).
// ---------------------------------------------------------------------------
__global__ __launch_bounds__(256) void k_e1(
    const float* __restrict__ mask, uint32* __restrict__ ecnt,
    uint8_t* __restrict__ et, float* __restrict__ ew)
{
    uint32 m = blockIdx.x * 256 + threadIdx.x;
    int cnt = 0;
    for (int t = 0; t < 128; ++t) {
        float w = mask[(size_t)t * 524288 + m];
        if (w != 0.0f) {
            if (cnt < 8) {
                et[(size_t)m * 8 + cnt] = (uint8_t)t;
                ew[(size_t)m * 8 + cnt] = w;
            }
            cnt++;
        }
    }
    ecnt[m] = (uint32)(cnt < 8 ? cnt : 8);
}

// ---------------------------------------------------------------------------
// E2: merge per (i,j): taps over all 32 s -> packed {w_bits, byte_off} (<=192).
// ---------------------------------------------------------------------------
__global__ void k_e2(const uint32* __restrict__ ecnt, const uint8_t* __restrict__ et,
                     const float* __restrict__ ew, uint32* __restrict__ cntij,
                     int2* __restrict__ taps)
{
    int lane = threadIdx.x & 31;
    int col = blockIdx.x * 2 + (threadIdx.x >> 5);
    uint32 m = (uint32)lane * 16384u + (uint32)col;
    int c = (int)ecnt[m];
    int v = c;
    for (int d = 1; d < 32; d <<= 1) {
        int t = __shfl_up(v, d, 32);
        if (lane >= d) v += t;
    }
    int off = v - c;
    if (lane == 31) cntij[col] = (uint32)v;
    for (int k = 0; k < c; ++k) {
        int2 r;
        r.x = __float_as_int(ew[(size_t)m * 8 + k]);
        r.y = ((lane << 7) + (int)et[(size_t)m * 8 + k]) << 12;   // st * 4096 bytes
        taps[(size_t)col * 192 + off + k] = r;
    }
}

// ---------------------------------------------------------------------------
// k_wt: transpose conv3x3 weights (COUT=64, CIN, 3, 3) -> wT[(cin*9+kk)*64+cout]
// ---------------------------------------------------------------------------
__global__ __launch_bounds__(256) void k_wt(
    const float* __restrict__ w, float* __restrict__ wT, int CIN)
{
    int n = blockIdx.x * 256 + threadIdx.x;
    int total = 64 * CIN * 9;
    if (n >= total) return;
    int per = CIN * 9;
    int cout = n / per;
    int rem = n - cout * per;     // cin*9 + kk
    wT[(size_t)rem * 64 + cout] = w[n];
}

// ---------------------------------------------------------------------------
// k_wab: cast wa (128x512 fp32) -> bf16, same row-major layout.
// ---------------------------------------------------------------------------
__global__ __launch_bounds__(256) void k_wab(
    const float* __restrict__ wa, ushort* __restrict__ waB)
{
    int n = blockIdx.x * 256 + threadIdx.x;   // 65536 total
    waB[n] = f2bf(wa[n]);
}

// ---------------------------------------------------------------------------
// k_bm (round-7 proven config): cm2[ij, bo] = relu(b3d[o] + sum w*H2t[st,bo])
// Thread owns bo-pair; taps broadcast from LDS. Grid (x=boT 8, y=i*4+quarter).
// ---------------------------------------------------------------------------
__global__ __launch_bounds__(128) void k_bm(
    const ushort* __restrict__ h2t, const int2* __restrict__ taps,
    const uint32* __restrict__ cntij, const float* __restrict__ b3d,
    ushort* __restrict__ cm2)
{
    __shared__ int2 tl[8 * 192];        // 12,288 B
    int boT = blockIdx.x;
    int i = blockIdx.y >> 2, q = blockIdx.y & 3;
    int tid = threadIdx.x;
    int bo0 = boT * 256 + tid * 2;
    const char* hb = (const char*)h2t + (size_t)bo0 * 2;
    float bias0 = b3d[bo0 & 511];
    float bias1 = b3d[(bo0 & 511) + 1];
    uint32* cm32 = (uint32*)cm2;

    for (int jc = 0; jc < 4; ++jc) {
        int j0 = q * 32 + jc * 8;
        int ij0 = i * 128 + j0;
        int cnts[8];
#pragma unroll
        for (int c = 0; c < 8; ++c) cnts[c] = (int)cntij[ij0 + c];
        __syncthreads();   // previous chunk's readers done before tl overwrite
        for (int n = tid; n < 1536; n += 128) {
            int c = n / 192, k = n - c * 192;
            if (k < cnts[c]) tl[n] = taps[(size_t)(ij0 + c) * 192 + k];
        }
        __syncthreads();
#pragma unroll 1
        for (int c = 0; c < 8; ++c) {
            int cnt = cnts[c];
            const int2* tp = &tl[c * 192];
            float a0 = 0.0f, a1 = 0.0f;
#pragma unroll 16
            for (int k = 0; k < cnt; ++k) {
                int2 r = tp[k];
                uint32 hv = *(const uint32*)(hb + (uint32)r.y);
                float w = __int_as_float(r.x);
                a0 += w * __uint_as_float(hv << 16);
                a1 += w * __uint_as_float(hv & 0xffff0000u);
            }
            float v0 = a0 + bias0; v0 = v0 > 0.0f ? v0 : 0.0f;
            float v1 = a1 + bias1; v1 = v1 > 0.0f ? v1 : 0.0f;
            uint32 pr = (uint32)f2bf(v0) | ((uint32)f2bf(v1) << 16);
            __builtin_nontemporal_store(pr, &cm32[((size_t)(ij0 + c) * 2048 + bo0) >> 1]);
        }
    }
}

// ---------------------------------------------------------------------------
// conv-a via MFMA: p1[b,c,ij] = relu(ba[c] + sum_o waB[c,o]*cm2[ij, b*512+o])
// GEMM per batch: M=c(128), N=ij(16384), K=o(512). Block 256 thr = 4 waves;
// wave owns a 128x16 output column tile (8 MFMA accs); K contiguous in both
// operands -> direct bf16x8 global loads, no LDS, no barriers.
// D layout (HW-verified): col=lane&15 (ij), row=(lane>>4)*4+reg (c).
// ---------------------------------------------------------------------------
__global__ __launch_bounds__(256) void k_convaM(
    const ushort* __restrict__ cm2, const ushort* __restrict__ waB,
    const float* __restrict__ ba, float* __restrict__ p1)
{
    int b = blockIdx.y;
    int wv = threadIdx.x >> 6, l = threadIdx.x & 63;
    int ij0 = blockIdx.x * 64 + wv * 16;
    int l15 = l & 15, g = l >> 4;

    f32x4 acc[8];
#pragma unroll
    for (int m = 0; m < 8; ++m) acc[m] = (f32x4){0.f, 0.f, 0.f, 0.f};

    const ushort* bbase = cm2 + (size_t)(ij0 + l15) * 2048 + b * 512 + g * 8;
    const ushort* abase = waB + (size_t)l15 * 512 + g * 8;

#pragma unroll 2
    for (int o0 = 0; o0 < 512; o0 += 32) {
        bf16x8 bv = *(const bf16x8*)(bbase + o0);
#pragma unroll
        for (int m = 0; m < 8; ++m) {
            bf16x8 av = *(const bf16x8*)(abase + (size_t)(m * 16) * 512 + o0);
            acc[m] = __builtin_amdgcn_mfma_f32_16x16x32_bf16(av, bv, acc[m], 0, 0, 0);
        }
    }

    int ij = ij0 + l15;
#pragma unroll
    for (int m = 0; m < 8; ++m) {
        int c = m * 16 + g * 4;
#pragma unroll
        for (int r = 0; r < 4; ++r) {
            float v = acc[m][r] + ba[c + r];
            v = v > 0.0f ? v : 0.0f;
            p1[((size_t)(b * 128 + c + r)) * 16384 + ij] = v;
        }
    }
}

// ---------------------------------------------------------------------------
// 3x3 conv, CIN -> 64, pad 1, relu (round-8 proven config). Weights from
// pre-transposed wT ([cin][kk][cout]); div-free coalesced staging.
// ---------------------------------------------------------------------------
template <int CIN>
__global__ __launch_bounds__(256) void k_conv3x3(
    const float* __restrict__ in, const float* __restrict__ wT,
    const float* __restrict__ bias, float* __restrict__ out)
{
    __shared__ float lx[8][3 * 132];   // 8 ch x 3 rows, padded cols 0..129
    __shared__ float lwsf[4608];       // [ch*9 + kk][64 couts]
    int i = blockIdx.x, b = blockIdx.y;
    int cg = threadIdx.x >> 4, jg = threadIdx.x & 15;
    int c0 = cg * 4, j0 = jg * 8;
    int sch = threadIdx.x >> 5, sl = threadIdx.x & 31;
    float acc[4][8];
#pragma unroll
    for (int cc = 0; cc < 4; ++cc)
#pragma unroll
        for (int k = 0; k < 8; ++k) acc[cc][k] = 0.0f;

    for (int o0 = 0; o0 < CIN; o0 += 8) {
        __syncthreads();
        {
            const float* src = in + (size_t)(b * CIN + o0 + sch) * 16384;
#pragma unroll
            for (int r = 0; r < 3; ++r) {
                int ii = i + r - 1;
                bool rowok = (ii >= 0) && (ii < 128);
#pragma unroll
                for (int p = 0; p < 5; ++p) {
                    int col = p * 32 + sl;
                    if (col < 130) {
                        int jj = col - 1;
                        float v = 0.0f;
                        if (rowok && jj >= 0 && jj < 128)
                            v = src[ii * 128 + jj];
                        lx[sch][r * 132 + col] = v;
                    }
                }
            }
        }
        {
            const float* wsrc = wT + (size_t)o0 * 576;   // 72 rows x 64 couts
            for (int n = threadIdx.x; n < 4608; n += 256)
                lwsf[n] = wsrc[n];
        }
        __syncthreads();

#pragma unroll 1
        for (int ch = 0; ch < 8; ++ch) {
            float x0[10], x1[10], x2[10];
#pragma unroll
            for (int k = 0; k < 10; ++k) {
                x0[k] = lx[ch][0 * 132 + j0 + k];
                x1[k] = lx[ch][1 * 132 + j0 + k];
                x2[k] = lx[ch][2 * 132 + j0 + k];
            }
#pragma unroll
            for (int cc = 0; cc < 4; ++cc) {
                const float* wp = &lwsf[ch * 576 + c0 + cc];
                float w00 = wp[0],   w01 = wp[64],  w02 = wp[128];
                float w10 = wp[192], w11 = wp[256], w12 = wp[320];
                float w20 = wp[384], w21 = wp[448], w22 = wp[512];
#pragma unroll
                for (int k = 0; k < 8; ++k) {
                    acc[cc][k] += w00 * x0[k] + w01 * x0[k + 1] + w02 * x0[k + 2]
                                + w10 * x1[k] + w11 * x1[k + 1] + w12 * x1[k + 2]
                                + w20 * x2[k] + w21 * x2[k + 1] + w22 * x2[k + 2];
                }
            }
        }
    }
#pragma unroll
    for (int cc = 0; cc < 4; ++cc) {
        float bb = bias[c0 + cc];
#pragma unroll
        for (int k = 0; k < 8; ++k) {
            float v = acc[cc][k] + bb;
            v = v > 0.0f ? v : 0.0f;
            out[((size_t)(b * 64 + c0 + cc) * 128 + i) * 128 + j0 + k] = v;
        }
    }
}

// ---------------------------------------------------------------------------
// conv-d: 1x1, 64 -> 4, sigmoid, scatter to d_out floats
// ---------------------------------------------------------------------------
__global__ __launch_bounds__(256) void k_convd(
    const float* __restrict__ p3, const float* __restrict__ wd,
    const float* __restrict__ bd, float* __restrict__ outp)
{
    __shared__ float lw[256];
    int b = blockIdx.y;
    int ij = blockIdx.x * 256 + threadIdx.x;
    lw[threadIdx.x] = wd[threadIdx.x];
    __syncthreads();
    float a0 = bd[0], a1 = bd[1], a2 = bd[2], a3 = bd[3];
    for (int c = 0; c < 64; ++c) {
        float v = p3[((size_t)(b * 64 + c)) * 16384 + ij];
        a0 += lw[c] * v;
        a1 += lw[64 + c] * v;
        a2 += lw[128 + c] * v;
        a3 += lw[192 + c] * v;
    }
    outp[1536 + (size_t)(b * 2 + 0) * 16384 + ij] = sigmoidf(a2);  // iou ch0
    outp[1536 + (size_t)(b * 2 + 1) * 16384 + ij] = sigmoidf(a3);  // iou ch1
    outp[132608 + (size_t)b * 16384 + ij] = sigmoidf(a0);          // prop_start
    outp[198144 + (size_t)b * 16384 + ij] = sigmoidf(a1);          // prop_end
}

// ---------------------------------------------------------------------------
extern "C" void kernel_launch(void* const* d_in, const int* in_sizes, int n_in,
                              void* d_out, int out_size, void* d_ws, size_t ws_size,
                              hipStream_t stream)
{
    const float* x   = (const float*)d_in[0];
    const float* w1  = (const float*)d_in[1];
    const float* b1  = (const float*)d_in[2];
    const float* w2  = (const float*)d_in[3];
    const float* b2  = (const float*)d_in[4];
    const float* w3  = (const float*)d_in[5];
    const float* b3  = (const float*)d_in[6];
    const float* w3d = (const float*)d_in[7];
    const float* b3d = (const float*)d_in[8];
    const float* wa  = (const float*)d_in[9];
    const float* ba  = (const float*)d_in[10];
    const float* wb  = (const float*)d_in[11];
    const float* bb  = (const float*)d_in[12];
    const float* wc  = (const float*)d_in[13];
    const float* bc  = (const float*)d_in[14];
    const float* wd  = (const float*)d_in[15];
    const float* bd  = (const float*)d_in[16];
    const float* sm  = (const float*)d_in[17];
    float* outp = (float*)d_out;
    char* ws = (char*)d_ws;

    // workspace layout (with aliasing; peak ~127.3 MB)
    float*  h1    = (float*)(ws + 0);              //  1,048,576 B
    float*  h     = (float*)(ws + 1048576);        //    262,144 B
    ushort* h2t   = (ushort*)(ws + 1310720);       // 16,777,216 B
    uint32* ecnt  = (uint32*)(ws + 18087936);      //  2,097,152 B
    uint8_t* et   = (uint8_t*)(ws + 20185088);     //  4,194,304 B
    float*  ewf   = (float*)(ws + 24379392);       // 16,777,216 B (dead after e2)
    uint32* cntij = (uint32*)(ws + 41156608);      //     65,536 B
    int2*   taps  = (int2*)(ws + 41222144);        // 25,165,824 B
    ushort* cm2   = (ushort*)(ws + 66387968);      // 67,108,864 B  [ij][bo]
    float*  p1    = (float*)(ws + 1310720);        // 33,554,432 B (aliases h2t+e-bufs)
    float*  p2    = (float*)(ws + 41222144);       // 16,777,216 B (aliases taps)
    float*  p3    = (float*)(ws + 66387968);       // 16,777,216 B (aliases cm2)
    float*  wbT   = (float*)(ws + 34865152);       //    294,912 B (dead-ewf zone, > p1 end)
    float*  wcT   = (float*)(ws + 35160064);       //    147,456 B
    ushort* waB   = (ushort*)(ws + 35307520);      //    131,072 B (ends < cntij)

    dim3 blk(256);
    k_conv1d_relu<<<dim3(32, 4), blk, 0, stream>>>(x, w1, b1, h1, 200, 400, 512);
    k_conv1d_relu<<<dim3(8, 4), blk, 0, stream>>>(h1, w2, b2, h, 512, 512, 128);
    k_x4<<<1, 512, 0, stream>>>(h, w3, b3, outp);
    k_h2<<<dim3(8, 32, 4), blk, 0, stream>>>(h, w3d, h2t);
    k_e1<<<2048, blk, 0, stream>>>(sm, ecnt, et, ewf);
    k_e2<<<8192, 64, 0, stream>>>(ecnt, et, ewf, cntij, taps);
    k_wt<<<288, blk, 0, stream>>>(wb, wbT, 128);
    k_wt<<<144, blk, 0, stream>>>(wc, wcT, 64);
    k_wab<<<256, blk, 0, stream>>>(wa, waB);
    k_bm<<<dim3(8, 512), dim3(128), 0, stream>>>(h2t, taps, cntij, b3d, cm2);
    k_convaM<<<dim3(256, 4), blk, 0, stream>>>(cm2, waB, ba, p1);
    k_conv3x3<128><<<dim3(128, 4), blk, 0, stream>>>(p1, wbT, bb, p2);
    k_conv3x3<64><<<dim3(128, 4), blk, 0, stream>>>(p2, wcT, bc, p3);
    k_convd<<<dim3(64, 4), blk, 0, stream>>>(p3, wd, bd, outp);
}

// Round 11
// 871.113 us; speedup vs baseline: 1.3856x; 1.1592x over previous
//
#include <hip/hip_runtime.h>
#include <hip/hip_bf16.h>
#include <stdint.h>

// ---------------------------------------------------------------------------
// Problem geometry
//   x (4,400,128) -> conv1d(200->512,k3,p1,relu) -> conv1d(512->128,k3,p1,relu) = h
//   x4 = sigmoid(0.01*conv1d(h, w3(3,128,1))) -> outputs xc(ch2), xb_start(ch0), xb_end(ch1)
//   cm = einsum('bct,tm->bcm', h, mask) ; conv3d(w3d, stride 32) + b3d, relu
//     == relu(b3d[o] + sum_{s,t} mask[t,s,i,j] * H2[b,o,s,t])   (<=6 taps/(s,i,j))
//   then 1x1(512->128,relu) [MFMA], 3x3(128->64,relu) [MFMA], 3x3(64->64,relu)
//   [MFMA], 1x1(64->4,sigmoid)
//   outputs (float32): xc,xb_start,xb_end (3*512) | iou (4,2,128,128) | prop_start | prop_end
//
// cm stored TRANSPOSED: cm2[ij][bo]. k_bm (round-7 proven config): 128-thr
// blocks, thread owns bo-pair, taps broadcast from LDS, grid (x=boT 8 ->
// XCD-pinned 2MB h2t slice, y = i*4 + quarter).
// MFMA fragment mapping (HW-validated by round-10 conva): A row=lane&15,
// k=(lane>>4)*8+e; B col=lane&15; D col=lane&15, row=(lane>>4)*4+reg.
// Activations for MFMA convs kept in [ij][cin] bf16 (cin contiguous).
// ---------------------------------------------------------------------------

typedef unsigned int uint32;
typedef __attribute__((ext_vector_type(8))) short bf16x8;
typedef __attribute__((ext_vector_type(4))) float f32x4;

__device__ __forceinline__ float bf2f(ushort u) {
    return __uint_as_float(((uint32)u) << 16);
}
__device__ __forceinline__ ushort f2bf(float f) {
    uint32 x = __float_as_uint(f);
    uint32 r = (x + 0x7FFFu + ((x >> 16) & 1u)) >> 16;
    return (ushort)r;
}
__device__ __forceinline__ float sigmoidf(float x) {
    return 1.0f / (1.0f + __expf(-x));
}

// ---------------------------------------------------------------------------
// conv1d (k=3, pad=1, relu). Block: 16 out-channels x 128 t. Grid (COUT/16, B).
// ---------------------------------------------------------------------------
__global__ __launch_bounds__(256) void k_conv1d_relu(
    const float* __restrict__ in, const float* __restrict__ w,
    const float* __restrict__ bias, float* __restrict__ out,
    int CIN, int in_batch_stride, int COUT)
{
    __shared__ float lx[64 * 132];   // [c][0..127 data, 128 = zero pad]
    int b  = blockIdx.y;
    int o  = blockIdx.x * 16 + (threadIdx.x >> 4);
    int tg = threadIdx.x & 15;
    int t0 = tg * 8;

    float acc[8];
#pragma unroll
    for (int k = 0; k < 8; ++k) acc[k] = 0.0f;

    for (int c0 = 0; c0 < CIN; c0 += 64) {
        int nc = CIN - c0; if (nc > 64) nc = 64;
        __syncthreads();
        for (int n = threadIdx.x; n < nc * 32; n += 256) {
            int cl = n >> 5, q = n & 31;
            float4 v = *(const float4*)(in + ((size_t)(b * in_batch_stride + c0 + cl)) * 128 + q * 4);
            *(float4*)(&lx[cl * 132 + q * 4]) = v;
        }
        for (int cl = threadIdx.x; cl < nc; cl += 256) lx[cl * 132 + 128] = 0.0f;
        __syncthreads();

        for (int cl = 0; cl < nc; ++cl) {
            int c = c0 + cl;
            const float* wp = w + ((size_t)o * CIN + c) * 3;
            float w0 = wp[0], w1 = wp[1], w2 = wp[2];
            const float* row = &lx[cl * 132];
            float xv[10];
            if (t0 == 0) {
                xv[0] = 0.0f;
#pragma unroll
                for (int k = 1; k < 10; ++k) xv[k] = row[k - 1];
            } else {
#pragma unroll
                for (int k = 0; k < 10; ++k) xv[k] = row[t0 - 1 + k];
            }
#pragma unroll
            for (int k = 0; k < 8; ++k)
                acc[k] += w0 * xv[k] + w1 * xv[k + 1] + w2 * xv[k + 2];
        }
    }
    float bo = bias[o];
#pragma unroll
    for (int k = 0; k < 8; ++k) {
        float v = acc[k] + bo;
        out[((size_t)(b * COUT + o)) * 128 + t0 + k] = v > 0.0f ? v : 0.0f;
    }
}

// ---------------------------------------------------------------------------
// x4 head -> d_out[0:1536] floats: (xc=ch2 | xb_start=ch0 | xb_end=ch1)
// ---------------------------------------------------------------------------
__global__ void k_x4(const float* __restrict__ h, const float* __restrict__ w3,
                     const float* __restrict__ b3, float* __restrict__ outp)
{
    int tid = threadIdx.x;
    int b = tid >> 7, t = tid & 127;
    float a0 = 0.f, a1 = 0.f, a2 = 0.f;
    for (int c = 0; c < 128; ++c) {
        float hv = h[((size_t)(b * 128 + c)) * 128 + t];
        a0 += w3[c] * hv;
        a1 += w3[128 + c] * hv;
        a2 += w3[256 + c] * hv;
    }
    float s0 = sigmoidf(0.01f * (a0 + b3[0]));
    float s1 = sigmoidf(0.01f * (a1 + b3[1]));
    float s2 = sigmoidf(0.01f * (a2 + b3[2]));
    int bt = b * 128 + t;
    outp[bt]        = s2;   // xc
    outp[512 + bt]  = s0;   // xb_start
    outp[1024 + bt] = s1;   // xb_end
}

// ---------------------------------------------------------------------------
// H2t[(s*128+t)*2048 + b*512+o] = bf16( sum_c w3d[o,c,s]*h[b,c,t] )
// ---------------------------------------------------------------------------
__global__ __launch_bounds__(256) void k_h2(
    const float* __restrict__ h, const float* __restrict__ w3d,
    ushort* __restrict__ h2t)
{
    __shared__ float lw[64 * 129];     // [o][c]
    __shared__ float lhs[32 * 132];    // [c_local][t] ; reused as ushort out stage
    int ot = blockIdx.x, s = blockIdx.y, b = blockIdx.z;
    int o0 = ot * 64;

    for (int n = threadIdx.x; n < 8192; n += 256) {
        int o = n >> 7, c = n & 127;
        lw[o * 129 + c] = w3d[(size_t)(o0 + o) * 4096 + c * 32 + s];
    }

    int og = threadIdx.x >> 4, tg = threadIdx.x & 15;
    int o0t = og * 4, t0 = tg * 8;
    float acc[4][8];
#pragma unroll
    for (int oo = 0; oo < 4; ++oo)
#pragma unroll
        for (int k = 0; k < 8; ++k) acc[oo][k] = 0.0f;

    for (int c0 = 0; c0 < 128; c0 += 32) {
        __syncthreads();
        for (int n = threadIdx.x; n < 1024; n += 256) {
            int cl = n >> 5, q = n & 31;
            *(float4*)(&lhs[cl * 132 + q * 4]) =
                *(const float4*)(h + ((size_t)(b * 128 + c0 + cl)) * 128 + q * 4);
        }
        __syncthreads();
        for (int cl = 0; cl < 32; ++cl) {
            float hv[8];
#pragma unroll
            for (int k = 0; k < 8; ++k) hv[k] = lhs[cl * 132 + t0 + k];
#pragma unroll
            for (int oo = 0; oo < 4; ++oo) {
                float wv = lw[(o0t + oo) * 129 + c0 + cl];
#pragma unroll
                for (int k = 0; k < 8; ++k) acc[oo][k] += wv * hv[k];
            }
        }
    }
    __syncthreads();
    ushort* lout = (ushort*)lhs;       // [t*64 + o]
#pragma unroll
    for (int oo = 0; oo < 4; ++oo)
#pragma unroll
        for (int k = 0; k < 8; ++k)
            lout[(t0 + k) * 64 + o0t + oo] = f2bf(acc[oo][k]);
    __syncthreads();
    for (int n = threadIdx.x; n < 8192; n += 256) {
        int t = n >> 6, o = n & 63;
        h2t[(size_t)(s * 128 + t) * 2048 + b * 512 + o0 + o] = lout[n];
    }
}

// ---------------------------------------------------------------------------
// E1: per mask column m=(s,i,j), collect nonzero (t,w) taps (<=6 exist, cap 8).
// ---------------------------------------------------------------------------
__global__ __launch_bounds__(256) void k_e1(
    const float* __restrict__ mask, uint32* __restrict__ ecnt,
    uint8_t* __restrict__ et, float* __restrict__ ew)
{
    uint32 m = blockIdx.x * 256 + threadIdx.x;
    int cnt = 0;
    for (int t = 0; t < 128; ++t) {
        float w = mask[(size_t)t * 524288 + m];
        if (w != 0.0f) {
            if (cnt < 8) {
                et[(size_t)m * 8 + cnt] = (uint8_t)t;
                ew[(size_t)m * 8 + cnt] = w;
            }
            cnt++;
        }
    }
    ecnt[m] = (uint32)(cnt < 8 ? cnt : 8);
}

// ---------------------------------------------------------------------------
// E2: merge per (i,j): taps over all 32 s -> packed {w_bits, byte_off} (<=192).
// ---------------------------------------------------------------------------
__global__ void k_e2(const uint32* __restrict__ ecnt, const uint8_t* __restrict__ et,
                     const float* __restrict__ ew, uint32* __restrict__ cntij,
                     int2* __restrict__ taps)
{
    int lane = threadIdx.x & 31;
    int col = blockIdx.x * 2 + (threadIdx.x >> 5);
    uint32 m = (uint32)lane * 16384u + (uint32)col;
    int c = (int)ecnt[m];
    int v = c;
    for (int d = 1; d < 32; d <<= 1) {
        int t = __shfl_up(v, d, 32);
        if (lane >= d) v += t;
    }
    int off = v - c;
    if (lane == 31) cntij[col] = (uint32)v;
    for (int k = 0; k < c; ++k) {
        int2 r;
        r.x = __float_as_int(ew[(size_t)m * 8 + k]);
        r.y = ((lane << 7) + (int)et[(size_t)m * 8 + k]) << 12;   // st * 4096 bytes
        taps[(size_t)col * 192 + off + k] = r;
    }
}

// ---------------------------------------------------------------------------
// k_wt3: conv3x3 weights (64, CIN, 3, 3) fp32 -> bf16 [kk][cout][cin]
// (CIN is a power of two.)
// ---------------------------------------------------------------------------
__global__ __launch_bounds__(256) void k_wt3(
    const float* __restrict__ w, ushort* __restrict__ wB, int CIN)
{
    int n = blockIdx.x * 256 + threadIdx.x;
    int total = 64 * CIN * 9;
    if (n >= total) return;
    int kk = n % 9;
    int rest = n / 9;                  // cout*CIN + cin
    int cin = rest & (CIN - 1);
    int cout = rest / CIN;
    wB[((size_t)(kk * 64 + cout)) * CIN + cin] = f2bf(w[n]);
}

// ---------------------------------------------------------------------------
// k_wab: cast wa (128x512 fp32) -> bf16, same row-major layout.
// ---------------------------------------------------------------------------
__global__ __launch_bounds__(256) void k_wab(
    const float* __restrict__ wa, ushort* __restrict__ waB)
{
    int n = blockIdx.x * 256 + threadIdx.x;   // 65536 total
    waB[n] = f2bf(wa[n]);
}

// ---------------------------------------------------------------------------
// k_bm (round-7 proven config): cm2[ij, bo] = relu(b3d[o] + sum w*H2t[st,bo])
// Thread owns bo-pair; taps broadcast from LDS. Grid (x=boT 8, y=i*4+quarter).
// ---------------------------------------------------------------------------
__global__ __launch_bounds__(128) void k_bm(
    const ushort* __restrict__ h2t, const int2* __restrict__ taps,
    const uint32* __restrict__ cntij, const float* __restrict__ b3d,
    ushort* __restrict__ cm2)
{
    __shared__ int2 tl[8 * 192];        // 12,288 B
    int boT = blockIdx.x;
    int i = blockIdx.y >> 2, q = blockIdx.y & 3;
    int tid = threadIdx.x;
    int bo0 = boT * 256 + tid * 2;
    const char* hb = (const char*)h2t + (size_t)bo0 * 2;
    float bias0 = b3d[bo0 & 511];
    float bias1 = b3d[(bo0 & 511) + 1];
    uint32* cm32 = (uint32*)cm2;

    for (int jc = 0; jc < 4; ++jc) {
        int j0 = q * 32 + jc * 8;
        int ij0 = i * 128 + j0;
        int cnts[8];
#pragma unroll
        for (int c = 0; c < 8; ++c) cnts[c] = (int)cntij[ij0 + c];
        __syncthreads();   // previous chunk's readers done before tl overwrite
        for (int n = tid; n < 1536; n += 128) {
            int c = n / 192, k = n - c * 192;
            if (k < cnts[c]) tl[n] = taps[(size_t)(ij0 + c) * 192 + k];
        }
        __syncthreads();
#pragma unroll 1
        for (int c = 0; c < 8; ++c) {
            int cnt = cnts[c];
            const int2* tp = &tl[c * 192];
            float a0 = 0.0f, a1 = 0.0f;
#pragma unroll 16
            for (int k = 0; k < cnt; ++k) {
                int2 r = tp[k];
                uint32 hv = *(const uint32*)(hb + (uint32)r.y);
                float w = __int_as_float(r.x);
                a0 += w * __uint_as_float(hv << 16);
                a1 += w * __uint_as_float(hv & 0xffff0000u);
            }
            float v0 = a0 + bias0; v0 = v0 > 0.0f ? v0 : 0.0f;
            float v1 = a1 + bias1; v1 = v1 > 0.0f ? v1 : 0.0f;
            uint32 pr = (uint32)f2bf(v0) | ((uint32)f2bf(v1) << 16);
            __builtin_nontemporal_store(pr, &cm32[((size_t)(ij0 + c) * 2048 + bo0) >> 1]);
        }
    }
}

// ---------------------------------------------------------------------------
// conv-a via MFMA: p1b[b][ij][c] = bf16(relu(ba[c] + sum_o waB[c,o]*cm2[ij,b*512+o]))
// GEMM per batch: M=c(128), N=ij(16384), K=o(512). Block 256 thr = 4 waves;
// wave owns a 128x16 output column tile; K contiguous in both operands.
// ---------------------------------------------------------------------------
__global__ __launch_bounds__(256) void k_convaM(
    const ushort* __restrict__ cm2, const ushort* __restrict__ waB,
    const float* __restrict__ ba, ushort* __restrict__ p1b)
{
    int b = blockIdx.y;
    int wv = threadIdx.x >> 6, l = threadIdx.x & 63;
    int ij0 = blockIdx.x * 64 + wv * 16;
    int l15 = l & 15, g = l >> 4;

    f32x4 acc[8];
#pragma unroll
    for (int m = 0; m < 8; ++m) acc[m] = (f32x4){0.f, 0.f, 0.f, 0.f};

    const ushort* bbase = cm2 + (size_t)(ij0 + l15) * 2048 + b * 512 + g * 8;
    const ushort* abase = waB + (size_t)l15 * 512 + g * 8;

#pragma unroll 2
    for (int o0 = 0; o0 < 512; o0 += 32) {
        bf16x8 bv = *(const bf16x8*)(bbase + o0);
#pragma unroll
        for (int m = 0; m < 8; ++m) {
            bf16x8 av = *(const bf16x8*)(abase + (size_t)(m * 16) * 512 + o0);
            acc[m] = __builtin_amdgcn_mfma_f32_16x16x32_bf16(av, bv, acc[m], 0, 0, 0);
        }
    }

    int ij = ij0 + l15;
    ushort* ob = p1b + ((size_t)(b * 16384 + ij)) * 128;
#pragma unroll
    for (int m = 0; m < 8; ++m) {
        int c = m * 16 + g * 4;
        float v0 = fmaxf(acc[m][0] + ba[c], 0.f);
        float v1 = fmaxf(acc[m][1] + ba[c + 1], 0.f);
        float v2 = fmaxf(acc[m][2] + ba[c + 2], 0.f);
        float v3 = fmaxf(acc[m][3] + ba[c + 3], 0.f);
        uint2 pk;
        pk.x = (uint32)f2bf(v0) | ((uint32)f2bf(v1) << 16);
        pk.y = (uint32)f2bf(v2) | ((uint32)f2bf(v3) << 16);
        *(uint2*)(ob + c) = pk;
    }
}

// ---------------------------------------------------------------------------
// 3x3 conv via MFMA (implicit GEMM over 9 shifted taps):
//   out[c][ij] = relu(bias[c] + sum_{ky,kx,cin} wB[kk][c][cin]*inB[ij_sh][cin])
// inB: [b][ij][CIN] bf16. wB: [kk][64][CIN] bf16. Block 256 = 4 waves; wave
// owns 64c x 16ij. i uniform per block (ky validity = uniform branch); j+kx
// validity per-lane (zero B-fragment). OUT_BF16: p2b [b][ij][64] bf16; else
// fp32 [b*64+c][ij] for convd.
// ---------------------------------------------------------------------------
template <int CIN, int OUT_BF16>
__global__ __launch_bounds__(256) void k_conv3x3M(
    const ushort* __restrict__ inB, const ushort* __restrict__ wB,
    const float* __restrict__ bias, void* __restrict__ outp)
{
    int b = blockIdx.y;
    int wv = threadIdx.x >> 6, l = threadIdx.x & 63;
    int l15 = l & 15, g = l >> 4;
    int tile = blockIdx.x;                 // 0..255
    int i = tile >> 1;
    int j = (tile & 1) * 64 + wv * 16 + l15;
    const ushort* inb = inB + (size_t)b * 16384 * CIN;

    f32x4 acc[4];
#pragma unroll
    for (int m = 0; m < 4; ++m) acc[m] = (f32x4){0.f, 0.f, 0.f, 0.f};

#pragma unroll
    for (int ky = 0; ky < 3; ++ky) {
        int ii = i + ky - 1;
        if (ii < 0 || ii >= 128) continue;      // uniform per block
#pragma unroll
        for (int kx = 0; kx < 3; ++kx) {
            int jv = j + kx - 1;
            bool ok = (jv >= 0) && (jv < 128);  // per-lane
            const ushort* bp = inb + (size_t)(ii * 128 + jv) * CIN + g * 8;
            const ushort* ap = wB + (size_t)((ky * 3 + kx) * 64 + l15) * CIN + g * 8;
#pragma unroll
            for (int o0 = 0; o0 < CIN; o0 += 32) {
                bf16x8 bv;
                if (ok) bv = *(const bf16x8*)(bp + o0);
                else    bv = (bf16x8){0, 0, 0, 0, 0, 0, 0, 0};
#pragma unroll
                for (int m = 0; m < 4; ++m) {
                    bf16x8 av = *(const bf16x8*)(ap + (size_t)(m * 16) * CIN + o0);
                    acc[m] = __builtin_amdgcn_mfma_f32_16x16x32_bf16(av, bv, acc[m], 0, 0, 0);
                }
            }
        }
    }

    int ij = i * 128 + j;
    if (OUT_BF16) {
        ushort* ob = (ushort*)outp + ((size_t)(b * 16384 + ij)) * 64;
#pragma unroll
        for (int m = 0; m < 4; ++m) {
            int c = m * 16 + g * 4;
            float v0 = fmaxf(acc[m][0] + bias[c], 0.f);
            float v1 = fmaxf(acc[m][1] + bias[c + 1], 0.f);
            float v2 = fmaxf(acc[m][2] + bias[c + 2], 0.f);
            float v3 = fmaxf(acc[m][3] + bias[c + 3], 0.f);
            uint2 pk;
            pk.x = (uint32)f2bf(v0) | ((uint32)f2bf(v1) << 16);
            pk.y = (uint32)f2bf(v2) | ((uint32)f2bf(v3) << 16);
            *(uint2*)(ob + c) = pk;
        }
    } else {
        float* of = (float*)outp;
#pragma unroll
        for (int m = 0; m < 4; ++m) {
            int c = m * 16 + g * 4;
#pragma unroll
            for (int r = 0; r < 4; ++r) {
                float v = acc[m][r] + bias[c + r];
                v = v > 0.0f ? v : 0.0f;
                of[((size_t)(b * 64 + c + r)) * 16384 + ij] = v;
            }
        }
    }
}

// ---------------------------------------------------------------------------
// conv-d: 1x1, 64 -> 4, sigmoid, scatter to d_out floats
// ---------------------------------------------------------------------------
__global__ __launch_bounds__(256) void k_convd(
    const float* __restrict__ p3, const float* __restrict__ wd,
    const float* __restrict__ bd, float* __restrict__ outp)
{
    __shared__ float lw[256];
    int b = blockIdx.y;
    int ij = blockIdx.x * 256 + threadIdx.x;
    lw[threadIdx.x] = wd[threadIdx.x];
    __syncthreads();
    float a0 = bd[0], a1 = bd[1], a2 = bd[2], a3 = bd[3];
    for (int c = 0; c < 64; ++c) {
        float v = p3[((size_t)(b * 64 + c)) * 16384 + ij];
        a0 += lw[c] * v;
        a1 += lw[64 + c] * v;
        a2 += lw[128 + c] * v;
        a3 += lw[192 + c] * v;
    }
    outp[1536 + (size_t)(b * 2 + 0) * 16384 + ij] = sigmoidf(a2);  // iou ch0
    outp[1536 + (size_t)(b * 2 + 1) * 16384 + ij] = sigmoidf(a3);  // iou ch1
    outp[132608 + (size_t)b * 16384 + ij] = sigmoidf(a0);          // prop_start
    outp[198144 + (size_t)b * 16384 + ij] = sigmoidf(a1);          // prop_end
}

// ---------------------------------------------------------------------------
extern "C" void kernel_launch(void* const* d_in, const int* in_sizes, int n_in,
                              void* d_out, int out_size, void* d_ws, size_t ws_size,
                              hipStream_t stream)
{
    const float* x   = (const float*)d_in[0];
    const float* w1  = (const float*)d_in[1];
    const float* b1  = (const float*)d_in[2];
    const float* w2  = (const float*)d_in[3];
    const float* b2  = (const float*)d_in[4];
    const float* w3  = (const float*)d_in[5];
    const float* b3  = (const float*)d_in[6];
    const float* w3d = (const float*)d_in[7];
    const float* b3d = (const float*)d_in[8];
    const float* wa  = (const float*)d_in[9];
    const float* ba  = (const float*)d_in[10];
    const float* wb  = (const float*)d_in[11];
    const float* bb  = (const float*)d_in[12];
    const float* wc  = (const float*)d_in[13];
    const float* bc  = (const float*)d_in[14];
    const float* wd  = (const float*)d_in[15];
    const float* bd  = (const float*)d_in[16];
    const float* sm  = (const float*)d_in[17];
    float* outp = (float*)d_out;
    char* ws = (char*)d_ws;

    // workspace layout (with aliasing; peak ~127.3 MB)
    float*  h1    = (float*)(ws + 0);              //  1,048,576 B
    float*  h     = (float*)(ws + 1048576);        //    262,144 B
    ushort* h2t   = (ushort*)(ws + 1310720);       // 16,777,216 B
    uint32* ecnt  = (uint32*)(ws + 18087936);      //  2,097,152 B
    uint8_t* et   = (uint8_t*)(ws + 20185088);     //  4,194,304 B
    float*  ewf   = (float*)(ws + 24379392);       // 16,777,216 B (dead after e2)
    uint32* cntij = (uint32*)(ws + 41156608);      //     65,536 B
    int2*   taps  = (int2*)(ws + 41222144);        // 25,165,824 B
    ushort* cm2   = (ushort*)(ws + 66387968);      // 67,108,864 B  [ij][bo]
    ushort* p1b   = (ushort*)(ws + 1310720);       // 16,777,216 B (aliases h2t; dead then)
    ushort* p2b   = (ushort*)(ws + 41222144);      //  8,388,608 B (aliases taps; dead then)
    float*  p3    = (float*)(ws + 66387968);       // 16,777,216 B (aliases cm2; dead then)
    float*  wbBf  = (float*)0;                     // (unused)
    ushort* wbB   = (ushort*)(ws + 34865152);      //    147,456 B (dead-ewf zone, > p1b end)
    ushort* wcB   = (ushort*)(ws + 35012608);      //     73,728 B
    ushort* waB   = (ushort*)(ws + 35307520);      //    131,072 B (ends < cntij)
    (void)wbBf;

    dim3 blk(256);
    k_conv1d_relu<<<dim3(32, 4), blk, 0, stream>>>(x, w1, b1, h1, 200, 400, 512);
    k_conv1d_relu<<<dim3(8, 4), blk, 0, stream>>>(h1, w2, b2, h, 512, 512, 128);
    k_x4<<<1, 512, 0, stream>>>(h, w3, b3, outp);
    k_h2<<<dim3(8, 32, 4), blk, 0, stream>>>(h, w3d, h2t);
    k_e1<<<2048, blk, 0, stream>>>(sm, ecnt, et, ewf);
    k_e2<<<8192, 64, 0, stream>>>(ecnt, et, ewf, cntij, taps);
    k_wt3<<<288, blk, 0, stream>>>(wb, wbB, 128);
    k_wt3<<<144, blk, 0, stream>>>(wc, wcB, 64);
    k_wab<<<256, blk, 0, stream>>>(wa, waB);
    k_bm<<<dim3(8, 512), dim3(128), 0, stream>>>(h2t, taps, cntij, b3d, cm2);
    k_convaM<<<dim3(256, 4), blk, 0, stream>>>(cm2, waB, ba, p1b);
    k_conv3x3M<128, 1><<<dim3(256, 4), blk, 0, stream>>>(p1b, wbB, bb, (void*)p2b);
    k_conv3x3M<64, 0><<<dim3(256, 4), blk, 0, stream>>>(p2b, wcB, bc, (void*)p3);
    k_convd<<<dim3(64, 4), blk, 0, stream>>>(p3, wd, bd, outp);
}

// Round 12
// 833.623 us; speedup vs baseline: 1.4479x; 1.0450x over previous
//
#include <hip/hip_runtime.h>
#include <hip/hip_bf16.h>
#include <stdint.h>

// ---------------------------------------------------------------------------
// Problem geometry
//   x (4,400,128) -> conv1d(200->512,k3,p1,relu) -> conv1d(512->128,k3,p1,relu) = h
//   x4 = sigmoid(0.01*conv1d(h, w3(3,128,1))) -> outputs xc(ch2), xb_start(ch0), xb_end(ch1)
//   cm = einsum('bct,tm->bcm', h, mask) ; conv3d(w3d, stride 32) + b3d, relu
//     == relu(b3d[o] + sum_{s,t} mask[t,s,i,j] * H2[b,o,s,t])   (<=6 taps/(s,i,j))
//   then 1x1(512->128,relu) [MFMA], 3x3(128->64,relu) [MFMA], 3x3(64->64,relu)
//   [MFMA], 1x1(64->4,sigmoid)
//   outputs (float32): xc,xb_start,xb_end (3*512) | iou (4,2,128,128) | prop_start | prop_end
//
// cm stored TRANSPOSED: cm2[ij][bo]. k_bm: 64-thr single-wave blocks, thread
// owns a bo-QUAD (1 dwordx2 = 4 bf16 = 4 MACs/tap), taps broadcast from LDS
// (6 KB), grid (x=boT 8 -> XCD-pinned 2MB h2t slice, y = i*16 + oct8) =
// 16384 blocks (2x wave-capacity oversubscription for imbalance backfill).
// MFMA fragment mapping (HW-validated by round-10 conva): A row=lane&15,
// k=(lane>>4)*8+e; B col=lane&15; D col=lane&15, row=(lane>>4)*4+reg.
// Activations for MFMA convs kept in [ij][cin] bf16 (cin contiguous).
// ---------------------------------------------------------------------------

typedef unsigned int uint32;
typedef __attribute__((ext_vector_type(8))) short bf16x8;
typedef __attribute__((ext_vector_type(4))) float f32x4;

__device__ __forceinline__ float bf2f(ushort u) {
    return __uint_as_float(((uint32)u) << 16);
}
__device__ __forceinline__ ushort f2bf(float f) {
    uint32 x = __float_as_uint(f);
    uint32 r = (x + 0x7FFFu + ((x >> 16) & 1u)) >> 16;
    return (ushort)r;
}
__device__ __forceinline__ float sigmoidf(float x) {
    return 1.0f / (1.0f + __expf(-x));
}

// ---------------------------------------------------------------------------
// conv1d (k=3, pad=1, relu). Block: 16 out-channels x 128 t. Grid (COUT/16, B).
// ---------------------------------------------------------------------------
__global__ __launch_bounds__(256) void k_conv1d_relu(
    const float* __restrict__ in, const float* __restrict__ w,
    const float* __restrict__ bias, float* __restrict__ out,
    int CIN, int in_batch_stride, int COUT)
{
    __shared__ float lx[64 * 132];   // [c][0..127 data, 128 = zero pad]
    int b  = blockIdx.y;
    int o  = blockIdx.x * 16 + (threadIdx.x >> 4);
    int tg = threadIdx.x & 15;
    int t0 = tg * 8;

    float acc[8];
#pragma unroll
    for (int k = 0; k < 8; ++k) acc[k] = 0.0f;

    for (int c0 = 0; c0 < CIN; c0 += 64) {
        int nc = CIN - c0; if (nc > 64) nc = 64;
        __syncthreads();
        for (int n = threadIdx.x; n < nc * 32; n += 256) {
            int cl = n >> 5, q = n & 31;
            float4 v = *(const float4*)(in + ((size_t)(b * in_batch_stride + c0 + cl)) * 128 + q * 4);
            *(float4*)(&lx[cl * 132 + q * 4]) = v;
        }
        for (int cl = threadIdx.x; cl < nc; cl += 256) lx[cl * 132 + 128] = 0.0f;
        __syncthreads();

        for (int cl = 0; cl < nc; ++cl) {
            int c = c0 + cl;
            const float* wp = w + ((size_t)o * CIN + c) * 3;
            float w0 = wp[0], w1 = wp[1], w2 = wp[2];
            const float* row = &lx[cl * 132];
            float xv[10];
            if (t0 == 0) {
                xv[0] = 0.0f;
#pragma unroll
                for (int k = 1; k < 10; ++k) xv[k] = row[k - 1];
            } else {
#pragma unroll
                for (int k = 0; k < 10; ++k) xv[k] = row[t0 - 1 + k];
            }
#pragma unroll
            for (int k = 0; k < 8; ++k)
                acc[k] += w0 * xv[k] + w1 * xv[k + 1] + w2 * xv[k + 2];
        }
    }
    float bo = bias[o];
#pragma unroll
    for (int k = 0; k < 8; ++k) {
        float v = acc[k] + bo;
        out[((size_t)(b * COUT + o)) * 128 + t0 + k] = v > 0.0f ? v : 0.0f;
    }
}

// ---------------------------------------------------------------------------
// x4 head -> d_out[0:1536] floats: (xc=ch2 | xb_start=ch0 | xb_end=ch1)
// ---------------------------------------------------------------------------
__global__ void k_x4(const float* __restrict__ h, const float* __restrict__ w3,
                     const float* __restrict__ b3, float* __restrict__ outp)
{
    int tid = threadIdx.x;
    int b = tid >> 7, t = tid & 127;
    float a0 = 0.f, a1 = 0.f, a2 = 0.f;
    for (int c = 0; c < 128; ++c) {
        float hv = h[((size_t)(b * 128 + c)) * 128 + t];
        a0 += w3[c] * hv;
        a1 += w3[128 + c] * hv;
        a2 += w3[256 + c] * hv;
    }
    float s0 = sigmoidf(0.01f * (a0 + b3[0]));
    float s1 = sigmoidf(0.01f * (a1 + b3[1]));
    float s2 = sigmoidf(0.01f * (a2 + b3[2]));
    int bt = b * 128 + t;
    outp[bt]        = s2;   // xc
    outp[512 + bt]  = s0;   // xb_start
    outp[1024 + bt] = s1;   // xb_end
}

// ---------------------------------------------------------------------------
// H2t[(s*128+t)*2048 + b*512+o] = bf16( sum_c w3d[o,c,s]*h[b,c,t] )
// ---------------------------------------------------------------------------
__global__ __launch_bounds__(256) void k_h2(
    const float* __restrict__ h, const float* __restrict__ w3d,
    ushort* __restrict__ h2t)
{
    __shared__ float lw[64 * 129];     // [o][c]
    __shared__ float lhs[32 * 132];    // [c_local][t] ; reused as ushort out stage
    int ot = blockIdx.x, s = blockIdx.y, b = blockIdx.z;
    int o0 = ot * 64;

    for (int n = threadIdx.x; n < 8192; n += 256) {
        int o = n >> 7, c = n & 127;
        lw[o * 129 + c] = w3d[(size_t)(o0 + o) * 4096 + c * 32 + s];
    }

    int og = threadIdx.x >> 4, tg = threadIdx.x & 15;
    int o0t = og * 4, t0 = tg * 8;
    float acc[4][8];
#pragma unroll
    for (int oo = 0; oo < 4; ++oo)
#pragma unroll
        for (int k = 0; k < 8; ++k) acc[oo][k] = 0.0f;

    for (int c0 = 0; c0 < 128; c0 += 32) {
        __syncthreads();
        for (int n = threadIdx.x; n < 1024; n += 256) {
            int cl = n >> 5, q = n & 31;
            *(float4*)(&lhs[cl * 132 + q * 4]) =
                *(const float4*)(h + ((size_t)(b * 128 + c0 + cl)) * 128 + q * 4);
        }
        __syncthreads();
        for (int cl = 0; cl < 32; ++cl) {
            float hv[8];
#pragma unroll
            for (int k = 0; k < 8; ++k) hv[k] = lhs[cl * 132 + t0 + k];
#pragma unroll
            for (int oo = 0; oo < 4; ++oo) {
                float wv = lw[(o0t + oo) * 129 + c0 + cl];
#pragma unroll
                for (int k = 0; k < 8; ++k) acc[oo][k] += wv * hv[k];
            }
        }
    }
    __syncthreads();
    ushort* lout = (ushort*)lhs;       // [t*64 + o]
#pragma unroll
    for (int oo = 0; oo < 4; ++oo)
#pragma unroll
        for (int k = 0; k < 8; ++k)
            lout[(t0 + k) * 64 + o0t + oo] = f2bf(acc[oo][k]);
    __syncthreads();
    for (int n = threadIdx.x; n < 8192; n += 256) {
        int t = n >> 6, o = n & 63;
        h2t[(size_t)(s * 128 + t) * 2048 + b * 512 + o0 + o] = lout[n];
    }
}

// ---------------------------------------------------------------------------
// E1: per mask column m=(s,i,j), collect nonzero (t,w) taps (<=6 exist, cap 8).
// ---------------------------------------------------------------------------
__global__ __launch_bounds__(256) void k_e1(
    const float* __restrict__ mask, uint32* __restrict__ ecnt,
    uint8_t* __restrict__ et, float* __restrict__ ew)
{
    uint32 m = blockIdx.x * 256 + threadIdx.x;
    int cnt = 0;
    for (int t = 0; t < 128; ++t) {
        float w = mask[(size_t)t * 524288 + m];
        if (w != 0.0f) {
            if (cnt < 8) {
                et[(size_t)m * 8 + cnt] = (uint8_t)t;
                ew[(size_t)m * 8 + cnt] = w;
            }
            cnt++;
        }
    }
    ecnt[m] = (uint32)(cnt < 8 ? cnt : 8);
}

// ---------------------------------------------------------------------------
// E2: merge per (i,j): taps over all 32 s -> packed {w_bits, byte_off} (<=192).
// ---------------------------------------------------------------------------
__global__ void k_e2(const uint32* __restrict__ ecnt, const uint8_t* __restrict__ et,
                     const float* __restrict__ ew, uint32* __restrict__ cntij,
                     int2* __restrict__ taps)
{
    int lane = threadIdx.x & 31;
    int col = blockIdx.x * 2 + (threadIdx.x >> 5);
    uint32 m = (uint32)lane * 16384u + (uint32)col;
    int c = (int)ecnt[m];
    int v = c;
    for (int d = 1; d < 32; d <<= 1) {
        int t = __shfl_up(v, d, 32);
        if (lane >= d) v += t;
    }
    int off = v - c;
    if (lane == 31) cntij[col] = (uint32)v;
    for (int k = 0; k < c; ++k) {
        int2 r;
        r.x = __float_as_int(ew[(size_t)m * 8 + k]);
        r.y = ((lane << 7) + (int)et[(size_t)m * 8 + k]) << 12;   // st * 4096 bytes
        taps[(size_t)col * 192 + off + k] = r;
    }
}

// ---------------------------------------------------------------------------
// k_wt3: conv3x3 weights (64, CIN, 3, 3) fp32 -> bf16 [kk][cout][cin]
// (CIN is a power of two.)
// ---------------------------------------------------------------------------
__global__ __launch_bounds__(256) void k_wt3(
    const float* __restrict__ w, ushort* __restrict__ wB, int CIN)
{
    int n = blockIdx.x * 256 + threadIdx.x;
    int total = 64 * CIN * 9;
    if (n >= total) return;
    int kk = n % 9;
    int rest = n / 9;                  // cout*CIN + cin
    int cin = rest & (CIN - 1);
    int cout = rest / CIN;
    wB[((size_t)(kk * 64 + cout)) * CIN + cin] = f2bf(w[n]);
}

// ---------------------------------------------------------------------------
// k_wab: cast wa (128x512 fp32) -> bf16, same row-major layout.
// ---------------------------------------------------------------------------
__global__ __launch_bounds__(256) void k_wab(
    const float* __restrict__ wa, ushort* __restrict__ waB)
{
    int n = blockIdx.x * 256 + threadIdx.x;   // 65536 total
    waB[n] = f2bf(wa[n]);
}

// ---------------------------------------------------------------------------
// k_bm: cm2[ij, bo] = relu(b3d[o] + sum_taps w * H2t[st, bo])   (bf16 out)
// 64-thr single-wave blocks; thread owns bo-quad (dwordx2 = 4 bf16 = 4 MACs,
// 4 independent FMA chains). Taps broadcast from 6 KB LDS (4-col chunks).
// Grid (x=boT 8, y = i*16 + oct8): x fastest pins each 2MB h2t bo-slice to
// one XCD's L2; 16384 blocks = 2x wave-capacity oversubscription.
// ---------------------------------------------------------------------------
__global__ __launch_bounds__(64) void k_bm(
    const ushort* __restrict__ h2t, const int2* __restrict__ taps,
    const uint32* __restrict__ cntij, const float* __restrict__ b3d,
    ushort* __restrict__ cm2)
{
    __shared__ int2 tl[4 * 192];        // 6,144 B
    int boT = blockIdx.x;
    int i = blockIdx.y >> 4, oc = blockIdx.y & 15;
    int tid = threadIdx.x;
    int bo0 = boT * 256 + tid * 4;
    const char* hb = (const char*)h2t + (size_t)bo0 * 2;
    float4 bias = *(const float4*)(b3d + (bo0 & 511));

    for (int jc = 0; jc < 2; ++jc) {
        int j0 = oc * 8 + jc * 4;
        int ij0 = i * 128 + j0;
        int cnts[4];
#pragma unroll
        for (int c = 0; c < 4; ++c) cnts[c] = (int)cntij[ij0 + c];
        __syncthreads();   // previous chunk's readers done before tl overwrite
        for (int n = tid; n < 768; n += 64) {
            int c = n / 192, k = n - c * 192;
            if (k < cnts[c]) tl[n] = taps[(size_t)(ij0 + c) * 192 + k];
        }
        __syncthreads();
#pragma unroll 1
        for (int c = 0; c < 4; ++c) {
            int cnt = cnts[c];
            const int2* tp = &tl[c * 192];
            float a0 = 0.f, a1 = 0.f, a2 = 0.f, a3 = 0.f;
#pragma unroll 8
            for (int k = 0; k < cnt; ++k) {
                int2 r = tp[k];
                uint2 hv = *(const uint2*)(hb + (uint32)r.y);
                float w = __int_as_float(r.x);
                a0 += w * __uint_as_float(hv.x << 16);
                a1 += w * __uint_as_float(hv.x & 0xffff0000u);
                a2 += w * __uint_as_float(hv.y << 16);
                a3 += w * __uint_as_float(hv.y & 0xffff0000u);
            }
            float v0 = fmaxf(a0 + bias.x, 0.f);
            float v1 = fmaxf(a1 + bias.y, 0.f);
            float v2 = fmaxf(a2 + bias.z, 0.f);
            float v3 = fmaxf(a3 + bias.w, 0.f);
            uint64_t pr = (uint64_t)((uint32)f2bf(v0) | ((uint32)f2bf(v1) << 16))
                        | ((uint64_t)((uint32)f2bf(v2) | ((uint32)f2bf(v3) << 16)) << 32);
            __builtin_nontemporal_store(pr, (uint64_t*)(cm2 + (size_t)(ij0 + c) * 2048 + bo0));
        }
    }
}

// ---------------------------------------------------------------------------
// conv-a via MFMA: p1b[b][ij][c] = bf16(relu(ba[c] + sum_o waB[c,o]*cm2[ij,b*512+o]))
// GEMM per batch: M=c(128), N=ij(16384), K=o(512). Block 256 thr = 4 waves;
// wave owns a 128x16 output column tile; K contiguous in both operands.
// ---------------------------------------------------------------------------
__global__ __launch_bounds__(256) void k_convaM(
    const ushort* __restrict__ cm2, const ushort* __restrict__ waB,
    const float* __restrict__ ba, ushort* __restrict__ p1b)
{
    int b = blockIdx.y;
    int wv = threadIdx.x >> 6, l = threadIdx.x & 63;
    int ij0 = blockIdx.x * 64 + wv * 16;
    int l15 = l & 15, g = l >> 4;

    f32x4 acc[8];
#pragma unroll
    for (int m = 0; m < 8; ++m) acc[m] = (f32x4){0.f, 0.f, 0.f, 0.f};

    const ushort* bbase = cm2 + (size_t)(ij0 + l15) * 2048 + b * 512 + g * 8;
    const ushort* abase = waB + (size_t)l15 * 512 + g * 8;

#pragma unroll 2
    for (int o0 = 0; o0 < 512; o0 += 32) {
        bf16x8 bv = *(const bf16x8*)(bbase + o0);
#pragma unroll
        for (int m = 0; m < 8; ++m) {
            bf16x8 av = *(const bf16x8*)(abase + (size_t)(m * 16) * 512 + o0);
            acc[m] = __builtin_amdgcn_mfma_f32_16x16x32_bf16(av, bv, acc[m], 0, 0, 0);
        }
    }

    int ij = ij0 + l15;
    ushort* ob = p1b + ((size_t)(b * 16384 + ij)) * 128;
#pragma unroll
    for (int m = 0; m < 8; ++m) {
        int c = m * 16 + g * 4;
        float v0 = fmaxf(acc[m][0] + ba[c], 0.f);
        float v1 = fmaxf(acc[m][1] + ba[c + 1], 0.f);
        float v2 = fmaxf(acc[m][2] + ba[c + 2], 0.f);
        float v3 = fmaxf(acc[m][3] + ba[c + 3], 0.f);
        uint2 pk;
        pk.x = (uint32)f2bf(v0) | ((uint32)f2bf(v1) << 16);
        pk.y = (uint32)f2bf(v2) | ((uint32)f2bf(v3) << 16);
        *(uint2*)(ob + c) = pk;
    }
}

// ---------------------------------------------------------------------------
// 3x3 conv via MFMA (implicit GEMM over 9 shifted taps):
//   out[c][ij] = relu(bias[c] + sum_{ky,kx,cin} wB[kk][c][cin]*inB[ij_sh][cin])
// inB: [b][ij][CIN] bf16. wB: [kk][64][CIN] bf16. Block 256 = 4 waves; wave
// owns 64c x 16ij. i uniform per block (ky validity = uniform branch); j+kx
// validity per-lane (zero B-fragment). OUT_BF16: p2b [b][ij][64] bf16; else
// fp32 [b*64+c][ij] for convd.
// ---------------------------------------------------------------------------
template <int CIN, int OUT_BF16>
__global__ __launch_bounds__(256) void k_conv3x3M(
    const ushort* __restrict__ inB, const ushort* __restrict__ wB,
    const float* __restrict__ bias, void* __restrict__ outp)
{
    int b = blockIdx.y;
    int wv = threadIdx.x >> 6, l = threadIdx.x & 63;
    int l15 = l & 15, g = l >> 4;
    int tile = blockIdx.x;                 // 0..255
    int i = tile >> 1;
    int j = (tile & 1) * 64 + wv * 16 + l15;
    const ushort* inb = inB + (size_t)b * 16384 * CIN;

    f32x4 acc[4];
#pragma unroll
    for (int m = 0; m < 4; ++m) acc[m] = (f32x4){0.f, 0.f, 0.f, 0.f};

#pragma unroll
    for (int ky = 0; ky < 3; ++ky) {
        int ii = i + ky - 1;
        if (ii < 0 || ii >= 128) continue;      // uniform per block
#pragma unroll
        for (int kx = 0; kx < 3; ++kx) {
            int jv = j + kx - 1;
            bool ok = (jv >= 0) && (jv < 128);  // per-lane
            const ushort* bp = inb + (size_t)(ii * 128 + jv) * CIN + g * 8;
            const ushort* ap = wB + (size_t)((ky * 3 + kx) * 64 + l15) * CIN + g * 8;
#pragma unroll
            for (int o0 = 0; o0 < CIN; o0 += 32) {
                bf16x8 bv;
                if (ok) bv = *(const bf16x8*)(bp + o0);
                else    bv = (bf16x8){0, 0, 0, 0, 0, 0, 0, 0};
#pragma unroll
                for (int m = 0; m < 4; ++m) {
                    bf16x8 av = *(const bf16x8*)(ap + (size_t)(m * 16) * CIN + o0);
                    acc[m] = __builtin_amdgcn_mfma_f32_16x16x32_bf16(av, bv, acc[m], 0, 0, 0);
                }
            }
        }
    }

    int ij = i * 128 + j;
    if (OUT_BF16) {
        ushort* ob = (ushort*)outp + ((size_t)(b * 16384 + ij)) * 64;
#pragma unroll
        for (int m = 0; m < 4; ++m) {
            int c = m * 16 + g * 4;
            float v0 = fmaxf(acc[m][0] + bias[c], 0.f);
            float v1 = fmaxf(acc[m][1] + bias[c + 1], 0.f);
            float v2 = fmaxf(acc[m][2] + bias[c + 2], 0.f);
            float v3 = fmaxf(acc[m][3] + bias[c + 3], 0.f);
            uint2 pk;
            pk.x = (uint32)f2bf(v0) | ((uint32)f2bf(v1) << 16);
            pk.y = (uint32)f2bf(v2) | ((uint32)f2bf(v3) << 16);
            *(uint2*)(ob + c) = pk;
        }
    } else {
        float* of = (float*)outp;
#pragma unroll
        for (int m = 0; m < 4; ++m) {
            int c = m * 16 + g * 4;
#pragma unroll
            for (int r = 0; r < 4; ++r) {
                float v = acc[m][r] + bias[c + r];
                v = v > 0.0f ? v : 0.0f;
                of[((size_t)(b * 64 + c + r)) * 16384 + ij] = v;
            }
        }
    }
}

// ---------------------------------------------------------------------------
// conv-d: 1x1, 64 -> 4, sigmoid, scatter to d_out floats
// ---------------------------------------------------------------------------
__global__ __launch_bounds__(256) void k_convd(
    const float* __restrict__ p3, const float* __restrict__ wd,
    const float* __restrict__ bd, float* __restrict__ outp)
{
    __shared__ float lw[256];
    int b = blockIdx.y;
    int ij = blockIdx.x * 256 + threadIdx.x;
    lw[threadIdx.x] = wd[threadIdx.x];
    __syncthreads();
    float a0 = bd[0], a1 = bd[1], a2 = bd[2], a3 = bd[3];
    for (int c = 0; c < 64; ++c) {
        float v = p3[((size_t)(b * 64 + c)) * 16384 + ij];
        a0 += lw[c] * v;
        a1 += lw[64 + c] * v;
        a2 += lw[128 + c] * v;
        a3 += lw[192 + c] * v;
    }
    outp[1536 + (size_t)(b * 2 + 0) * 16384 + ij] = sigmoidf(a2);  // iou ch0
    outp[1536 + (size_t)(b * 2 + 1) * 16384 + ij] = sigmoidf(a3);  // iou ch1
    outp[132608 + (size_t)b * 16384 + ij] = sigmoidf(a0);          // prop_start
    outp[198144 + (size_t)b * 16384 + ij] = sigmoidf(a1);          // prop_end
}

// ---------------------------------------------------------------------------
extern "C" void kernel_launch(void* const* d_in, const int* in_sizes, int n_in,
                              void* d_out, int out_size, void* d_ws, size_t ws_size,
                              hipStream_t stream)
{
    const float* x   = (const float*)d_in[0];
    const float* w1  = (const float*)d_in[1];
    const float* b1  = (const float*)d_in[2];
    const float* w2  = (const float*)d_in[3];
    const float* b2  = (const float*)d_in[4];
    const float* w3  = (const float*)d_in[5];
    const float* b3  = (const float*)d_in[6];
    const float* w3d = (const float*)d_in[7];
    const float* b3d = (const float*)d_in[8];
    const float* wa  = (const float*)d_in[9];
    const float* ba  = (const float*)d_in[10];
    const float* wb  = (const float*)d_in[11];
    const float* bb  = (const float*)d_in[12];
    const float* wc  = (const float*)d_in[13];
    const float* bc  = (const float*)d_in[14];
    const float* wd  = (const float*)d_in[15];
    const float* bd  = (const float*)d_in[16];
    const float* sm  = (const float*)d_in[17];
    float* outp = (float*)d_out;
    char* ws = (char*)d_ws;

    // workspace layout (with aliasing; peak ~127.3 MB)
    float*  h1    = (float*)(ws + 0);              //  1,048,576 B
    float*  h     = (float*)(ws + 1048576);        //    262,144 B
    ushort* h2t   = (ushort*)(ws + 1310720);       // 16,777,216 B
    uint32* ecnt  = (uint32*)(ws + 18087936);      //  2,097,152 B
    uint8_t* et   = (uint8_t*)(ws + 20185088);     //  4,194,304 B
    float*  ewf   = (float*)(ws + 24379392);       // 16,777,216 B (dead after e2)
    uint32* cntij = (uint32*)(ws + 41156608);      //     65,536 B
    int2*   taps  = (int2*)(ws + 41222144);        // 25,165,824 B
    ushort* cm2   = (ushort*)(ws + 66387968);      // 67,108,864 B  [ij][bo]
    ushort* p1b   = (ushort*)(ws + 1310720);       // 16,777,216 B (aliases h2t; dead then)
    ushort* p2b   = (ushort*)(ws + 41222144);      //  8,388,608 B (aliases taps; dead then)
    float*  p3    = (float*)(ws + 66387968);       // 16,777,216 B (aliases cm2; dead then)
    ushort* wbB   = (ushort*)(ws + 34865152);      //    147,456 B (dead-ewf zone, > p1b end)
    ushort* wcB   = (ushort*)(ws + 35012608);      //     73,728 B
    ushort* waB   = (ushort*)(ws + 35307520);      //    131,072 B (ends < cntij)

    dim3 blk(256);
    k_conv1d_relu<<<dim3(32, 4), blk, 0, stream>>>(x, w1, b1, h1, 200, 400, 512);
    k_conv1d_relu<<<dim3(8, 4), blk, 0, stream>>>(h1, w2, b2, h, 512, 512, 128);
    k_x4<<<1, 512, 0, stream>>>(h, w3, b3, outp);
    k_h2<<<dim3(8, 32, 4), blk, 0, stream>>>(h, w3d, h2t);
    k_e1<<<2048, blk, 0, stream>>>(sm, ecnt, et, ewf);
    k_e2<<<8192, 64, 0, stream>>>(ecnt, et, ewf, cntij, taps);
    k_wt3<<<288, blk, 0, stream>>>(wb, wbB, 128);
    k_wt3<<<144, blk, 0, stream>>>(wc, wcB, 64);
    k_wab<<<256, blk, 0, stream>>>(wa, waB);
    k_bm<<<dim3(8, 2048), dim3(64), 0, stream>>>(h2t, taps, cntij, b3d, cm2);
    k_convaM<<<dim3(256, 4), blk, 0, stream>>>(cm2, waB, ba, p1b);
    k_conv3x3M<128, 1><<<dim3(256, 4), blk, 0, stream>>>(p1b, wbB, bb, (void*)p2b);
    k_conv3x3M<64, 0><<<dim3(256, 4), blk, 0, stream>>>(p2b, wcB, bc, (void*)p3);
    k_convd<<<dim3(64, 4), blk, 0, stream>>>(p3, wd, bd, outp);
}

// Round 13
// 827.655 us; speedup vs baseline: 1.4583x; 1.0072x over previous
//
#include <hip/hip_runtime.h>
#include <hip/hip_bf16.h>
#include <stdint.h>

// ---------------------------------------------------------------------------
// Problem geometry
//   x (4,400,128) -> conv1d(200->512,k3,p1,relu) -> conv1d(512->128,k3,p1,relu) = h
//   x4 = sigmoid(0.01*conv1d(h, w3(3,128,1))) -> outputs xc(ch2), xb_start(ch0), xb_end(ch1)
//   cm = einsum('bct,tm->bcm', h, mask) ; conv3d(w3d, stride 32) + b3d, relu
//     == relu(b3d[o] + sum_{s,t} mask[t,s,i,j] * H2[b,o,s,t])   (<=6 taps/(s,i,j))
//   then 1x1(512->128,relu) [MFMA], 3x3(128->64,relu) [MFMA], 3x3(64->64,relu)
//   [MFMA], 1x1(64->4,sigmoid)
//   outputs (float32): xc,xb_start,xb_end (3*512) | iou (4,2,128,128) | prop_start | prop_end
//
// cm stored TRANSPOSED: cm2[ij][bo]. k_bm (round-12 proven): 64-thr single-wave
// blocks, bo-quad per thread, LDS tap broadcast, grid (8 XCD-pinned, 2048).
// conv1d: weights pre-transposed to [c*3+k][cout], LDS-staged (coalesced).
// h2: w3d pre-transposed to [s][o][c] so lw staging is contiguous float4.
// MFMA fragment mapping (HW-validated by round-10 conva): A row=lane&15,
// k=(lane>>4)*8+e; B col=lane&15; D col=lane&15, row=(lane>>4)*4+reg.
// ---------------------------------------------------------------------------

typedef unsigned int uint32;
typedef __attribute__((ext_vector_type(8))) short bf16x8;
typedef __attribute__((ext_vector_type(4))) float f32x4;

__device__ __forceinline__ float bf2f(ushort u) {
    return __uint_as_float(((uint32)u) << 16);
}
__device__ __forceinline__ ushort f2bf(float f) {
    uint32 x = __float_as_uint(f);
    uint32 r = (x + 0x7FFFu + ((x >> 16) & 1u)) >> 16;
    return (ushort)r;
}
__device__ __forceinline__ float sigmoidf(float x) {
    return 1.0f / (1.0f + __expf(-x));
}

// ---------------------------------------------------------------------------
// k_wtc: conv1d weights (COUT, CIN, 3) fp32 -> wT[(c*3+k)][COUT] fp32.
// Output-indexed: coalesced writes.
// ---------------------------------------------------------------------------
__global__ __launch_bounds__(256) void k_wtc(
    const float* __restrict__ w, float* __restrict__ wT, int CIN3, int COUT)
{
    int n = blockIdx.x * 256 + threadIdx.x;
    if (n >= CIN3 * COUT) return;
    int o = n % COUT, rem = n / COUT;
    wT[n] = w[(size_t)o * CIN3 + rem];
}

// ---------------------------------------------------------------------------
// k_wt5: w3d (512,128,32) fp32 -> w3dT[s][o][c] fp32. Output-indexed.
// ---------------------------------------------------------------------------
__global__ __launch_bounds__(256) void k_wt5(
    const float* __restrict__ w3d, float* __restrict__ w3dT)
{
    int n = blockIdx.x * 256 + threadIdx.x;    // (s*512+o)*128 + c
    int c = n & 127, o = (n >> 7) & 511, s = n >> 16;
    w3dT[n] = w3d[(size_t)o * 4096 + c * 32 + s];
}

// ---------------------------------------------------------------------------
// conv1d (k=3, pad=1, relu). Block: 16 out-channels x 128 t. Grid (COUT/16, B).
// Weights from wT[(c*3+k)][COUT], LDS-staged per 64-channel chunk.
// ---------------------------------------------------------------------------
__global__ __launch_bounds__(256) void k_conv1d_relu(
    const float* __restrict__ in, const float* __restrict__ wT,
    const float* __restrict__ bias, float* __restrict__ out,
    int CIN, int in_batch_stride, int COUT)
{
    __shared__ float lx[64 * 132];   // [c][0..127 data, 128 = zero pad]  33,792 B
    __shared__ float lws[64 * 48];   // [c][k][16 o]                      12,288 B
    int b  = blockIdx.y;
    int ooL = threadIdx.x >> 4;
    int o  = blockIdx.x * 16 + ooL;
    int tg = threadIdx.x & 15;
    int t0 = tg * 8;

    float acc[8];
#pragma unroll
    for (int k = 0; k < 8; ++k) acc[k] = 0.0f;

    for (int c0 = 0; c0 < CIN; c0 += 64) {
        int nc = CIN - c0; if (nc > 64) nc = 64;
        __syncthreads();
        for (int n = threadIdx.x; n < nc * 32; n += 256) {
            int cl = n >> 5, q = n & 31;
            float4 v = *(const float4*)(in + ((size_t)(b * in_batch_stride + c0 + cl)) * 128 + q * 4);
            *(float4*)(&lx[cl * 132 + q * 4]) = v;
        }
        for (int cl = threadIdx.x; cl < nc; cl += 256) lx[cl * 132 + 128] = 0.0f;
        for (int n = threadIdx.x; n < nc * 48; n += 256) {
            int cl = n / 48, r = n - cl * 48;       // r = k*16 + oo
            lws[n] = wT[((size_t)(c0 + cl) * 3 + (r >> 4)) * COUT + blockIdx.x * 16 + (r & 15)];
        }
        __syncthreads();

        for (int cl = 0; cl < nc; ++cl) {
            const float* wrow = &lws[cl * 48 + ooL];
            float w0 = wrow[0], w1 = wrow[16], w2 = wrow[32];
            const float* row = &lx[cl * 132];
            float xv[10];
            if (t0 == 0) {
                xv[0] = 0.0f;
#pragma unroll
                for (int k = 1; k < 10; ++k) xv[k] = row[k - 1];
            } else {
#pragma unroll
                for (int k = 0; k < 10; ++k) xv[k] = row[t0 - 1 + k];
            }
#pragma unroll
            for (int k = 0; k < 8; ++k)
                acc[k] += w0 * xv[k] + w1 * xv[k + 1] + w2 * xv[k + 2];
        }
    }
    float bo = bias[o];
#pragma unroll
    for (int k = 0; k < 8; ++k) {
        float v = acc[k] + bo;
        out[((size_t)(b * COUT + o)) * 128 + t0 + k] = v > 0.0f ? v : 0.0f;
    }
}

// ---------------------------------------------------------------------------
// x4 head -> d_out[0:1536] floats: (xc=ch2 | xb_start=ch0 | xb_end=ch1)
// ---------------------------------------------------------------------------
__global__ void k_x4(const float* __restrict__ h, const float* __restrict__ w3,
                     const float* __restrict__ b3, float* __restrict__ outp)
{
    int tid = threadIdx.x;
    int b = tid >> 7, t = tid & 127;
    float a0 = 0.f, a1 = 0.f, a2 = 0.f;
    for (int c = 0; c < 128; ++c) {
        float hv = h[((size_t)(b * 128 + c)) * 128 + t];
        a0 += w3[c] * hv;
        a1 += w3[128 + c] * hv;
        a2 += w3[256 + c] * hv;
    }
    float s0 = sigmoidf(0.01f * (a0 + b3[0]));
    float s1 = sigmoidf(0.01f * (a1 + b3[1]));
    float s2 = sigmoidf(0.01f * (a2 + b3[2]));
    int bt = b * 128 + t;
    outp[bt]        = s2;   // xc
    outp[512 + bt]  = s0;   // xb_start
    outp[1024 + bt] = s1;   // xb_end
}

// ---------------------------------------------------------------------------
// H2t[(s*128+t)*2048 + b*512+o] = bf16( sum_c w3dT[s][o][c]*h[b,c,t] )
// lw staged from w3dT with contiguous float4 copies.
// ---------------------------------------------------------------------------
__global__ __launch_bounds__(256) void k_h2(
    const float* __restrict__ h, const float* __restrict__ w3dT,
    ushort* __restrict__ h2t)
{
    __shared__ float lw[64 * 132];     // [o][c] stride 132                33,792 B
    __shared__ float lhs[32 * 132];    // [c_local][t] ; reused as out stage
    int ot = blockIdx.x, s = blockIdx.y, b = blockIdx.z;
    int o0 = ot * 64;

    for (int n = threadIdx.x; n < 2048; n += 256) {
        int o = n >> 5, q = n & 31;
        *(float4*)(&lw[o * 132 + q * 4]) =
            *(const float4*)(w3dT + ((size_t)(s * 512 + o0 + o)) * 128 + q * 4);
    }

    int og = threadIdx.x >> 4, tg = threadIdx.x & 15;
    int o0t = og * 4, t0 = tg * 8;
    float acc[4][8];
#pragma unroll
    for (int oo = 0; oo < 4; ++oo)
#pragma unroll
        for (int k = 0; k < 8; ++k) acc[oo][k] = 0.0f;

    for (int c0 = 0; c0 < 128; c0 += 32) {
        __syncthreads();
        for (int n = threadIdx.x; n < 1024; n += 256) {
            int cl = n >> 5, q = n & 31;
            *(float4*)(&lhs[cl * 132 + q * 4]) =
                *(const float4*)(h + ((size_t)(b * 128 + c0 + cl)) * 128 + q * 4);
        }
        __syncthreads();
        for (int cl = 0; cl < 32; ++cl) {
            float hv[8];
#pragma unroll
            for (int k = 0; k < 8; ++k) hv[k] = lhs[cl * 132 + t0 + k];
#pragma unroll
            for (int oo = 0; oo < 4; ++oo) {
                float wv = lw[(o0t + oo) * 132 + c0 + cl];
#pragma unroll
                for (int k = 0; k < 8; ++k) acc[oo][k] += wv * hv[k];
            }
        }
    }
    __syncthreads();
    ushort* lout = (ushort*)lhs;       // [t*64 + o]
#pragma unroll
    for (int oo = 0; oo < 4; ++oo)
#pragma unroll
        for (int k = 0; k < 8; ++k)
            lout[(t0 + k) * 64 + o0t + oo] = f2bf(acc[oo][k]);
    __syncthreads();
    for (int n = threadIdx.x; n < 8192; n += 256) {
        int t = n >> 6, o = n & 63;
        h2t[(size_t)(s * 128 + t) * 2048 + b * 512 + o0 + o] = lout[n];
    }
}

// ---------------------------------------------------------------------------
// E1: per mask column m=(s,i,j), collect nonzero (t,w) taps (<=6 exist, cap 8).
// ---------------------------------------------------------------------------
__global__ __launch_bounds__(256) void k_e1(
    const float* __restrict__ mask, uint32* __restrict__ ecnt,
    uint8_t* __restrict__ et, float* __restrict__ ew)
{
    uint32 m = blockIdx.x * 256 + threadIdx.x;
    int cnt = 0;
    for (int t = 0; t < 128; ++t) {
        float w = mask[(size_t)t * 524288 + m];
        if (w != 0.0f) {
            if (cnt < 8) {
                et[(size_t)m * 8 + cnt] = (uint8_t)t;
                ew[(size_t)m * 8 + cnt] = w;
            }
            cnt++;
        }
    }
    ecnt[m] = (uint32)(cnt < 8 ? cnt : 8);
}

// ---------------------------------------------------------------------------
// E2: merge per (i,j): taps over all 32 s -> packed {w_bits, byte_off} (<=192).
// ---------------------------------------------------------------------------
__global__ void k_e2(const uint32* __restrict__ ecnt, const uint8_t* __restrict__ et,
                     const float* __restrict__ ew, uint32* __restrict__ cntij,
                     int2* __restrict__ taps)
{
    int lane = threadIdx.x & 31;
    int col = blockIdx.x * 2 + (threadIdx.x >> 5);
    uint32 m = (uint32)lane * 16384u + (uint32)col;
    int c = (int)ecnt[m];
    int v = c;
    for (int d = 1; d < 32; d <<= 1) {
        int t = __shfl_up(v, d, 32);
        if (lane >= d) v += t;
    }
    int off = v - c;
    if (lane == 31) cntij[col] = (uint32)v;
    for (int k = 0; k < c; ++k) {
        int2 r;
        r.x = __float_as_int(ew[(size_t)m * 8 + k]);
        r.y = ((lane << 7) + (int)et[(size_t)m * 8 + k]) << 12;   // st * 4096 bytes
        taps[(size_t)col * 192 + off + k] = r;
    }
}

// ---------------------------------------------------------------------------
// k_wt3: conv3x3 weights (64, CIN, 3, 3) fp32 -> bf16 [kk][cout][cin]
// ---------------------------------------------------------------------------
__global__ __launch_bounds__(256) void k_wt3(
    const float* __restrict__ w, ushort* __restrict__ wB, int CIN)
{
    int n = blockIdx.x * 256 + threadIdx.x;
    int total = 64 * CIN * 9;
    if (n >= total) return;
    int kk = n % 9;
    int rest = n / 9;                  // cout*CIN + cin
    int cin = rest & (CIN - 1);
    int cout = rest / CIN;
    wB[((size_t)(kk * 64 + cout)) * CIN + cin] = f2bf(w[n]);
}

// ---------------------------------------------------------------------------
// k_wab: cast wa (128x512 fp32) -> bf16, same row-major layout.
// ---------------------------------------------------------------------------
__global__ __launch_bounds__(256) void k_wab(
    const float* __restrict__ wa, ushort* __restrict__ waB)
{
    int n = blockIdx.x * 256 + threadIdx.x;   // 65536 total
    waB[n] = f2bf(wa[n]);
}

// ---------------------------------------------------------------------------
// k_bm (round-12 proven): cm2[ij, bo] = relu(b3d[o] + sum w*H2t[st,bo])
// 64-thr single-wave blocks; bo-quad per thread (dwordx2 = 4 bf16 = 4 MACs).
// Taps broadcast from 6 KB LDS. Grid (x=boT 8 -> XCD-pinned 2MB h2t slice,
// y = i*16 + oct8) = 16384 blocks, 2x wave-capacity oversubscription.
// ---------------------------------------------------------------------------
__global__ __launch_bounds__(64) void k_bm(
    const ushort* __restrict__ h2t, const int2* __restrict__ taps,
    const uint32* __restrict__ cntij, const float* __restrict__ b3d,
    ushort* __restrict__ cm2)
{
    __shared__ int2 tl[4 * 192];        // 6,144 B
    int boT = blockIdx.x;
    int i = blockIdx.y >> 4, oc = blockIdx.y & 15;
    int tid = threadIdx.x;
    int bo0 = boT * 256 + tid * 4;
    const char* hb = (const char*)h2t + (size_t)bo0 * 2;
    float4 bias = *(const float4*)(b3d + (bo0 & 511));

    for (int jc = 0; jc < 2; ++jc) {
        int j0 = oc * 8 + jc * 4;
        int ij0 = i * 128 + j0;
        int cnts[4];
#pragma unroll
        for (int c = 0; c < 4; ++c) cnts[c] = (int)cntij[ij0 + c];
        __syncthreads();   // previous chunk's readers done before tl overwrite
        for (int n = tid; n < 768; n += 64) {
            int c = n / 192, k = n - c * 192;
            if (k < cnts[c]) tl[n] = taps[(size_t)(ij0 + c) * 192 + k];
        }
        __syncthreads();
#pragma unroll 1
        for (int c = 0; c < 4; ++c) {
            int cnt = cnts[c];
            const int2* tp = &tl[c * 192];
            float a0 = 0.f, a1 = 0.f, a2 = 0.f, a3 = 0.f;
#pragma unroll 8
            for (int k = 0; k < cnt; ++k) {
                int2 r = tp[k];
                uint2 hv = *(const uint2*)(hb + (uint32)r.y);
                float w = __int_as_float(r.x);
                a0 += w * __uint_as_float(hv.x << 16);
                a1 += w * __uint_as_float(hv.x & 0xffff0000u);
                a2 += w * __uint_as_float(hv.y << 16);
                a3 += w * __uint_as_float(hv.y & 0xffff0000u);
            }
            float v0 = fmaxf(a0 + bias.x, 0.f);
            float v1 = fmaxf(a1 + bias.y, 0.f);
            float v2 = fmaxf(a2 + bias.z, 0.f);
            float v3 = fmaxf(a3 + bias.w, 0.f);
            uint64_t pr = (uint64_t)((uint32)f2bf(v0) | ((uint32)f2bf(v1) << 16))
                        | ((uint64_t)((uint32)f2bf(v2) | ((uint32)f2bf(v3) << 16)) << 32);
            __builtin_nontemporal_store(pr, (uint64_t*)(cm2 + (size_t)(ij0 + c) * 2048 + bo0));
        }
    }
}

// ---------------------------------------------------------------------------
// conv-a via MFMA: p1b[b][ij][c] = bf16(relu(ba[c] + sum_o waB[c,o]*cm2[ij,b*512+o]))
// ---------------------------------------------------------------------------
__global__ __launch_bounds__(256) void k_convaM(
    const ushort* __restrict__ cm2, const ushort* __restrict__ waB,
    const float* __restrict__ ba, ushort* __restrict__ p1b)
{
    int b = blockIdx.y;
    int wv = threadIdx.x >> 6, l = threadIdx.x & 63;
    int ij0 = blockIdx.x * 64 + wv * 16;
    int l15 = l & 15, g = l >> 4;

    f32x4 acc[8];
#pragma unroll
    for (int m = 0; m < 8; ++m) acc[m] = (f32x4){0.f, 0.f, 0.f, 0.f};

    const ushort* bbase = cm2 + (size_t)(ij0 + l15) * 2048 + b * 512 + g * 8;
    const ushort* abase = waB + (size_t)l15 * 512 + g * 8;

#pragma unroll 2
    for (int o0 = 0; o0 < 512; o0 += 32) {
        bf16x8 bv = *(const bf16x8*)(bbase + o0);
#pragma unroll
        for (int m = 0; m < 8; ++m) {
            bf16x8 av = *(const bf16x8*)(abase + (size_t)(m * 16) * 512 + o0);
            acc[m] = __builtin_amdgcn_mfma_f32_16x16x32_bf16(av, bv, acc[m], 0, 0, 0);
        }
    }

    int ij = ij0 + l15;
    ushort* ob = p1b + ((size_t)(b * 16384 + ij)) * 128;
#pragma unroll
    for (int m = 0; m < 8; ++m) {
        int c = m * 16 + g * 4;
        float v0 = fmaxf(acc[m][0] + ba[c], 0.f);
        float v1 = fmaxf(acc[m][1] + ba[c + 1], 0.f);
        float v2 = fmaxf(acc[m][2] + ba[c + 2], 0.f);
        float v3 = fmaxf(acc[m][3] + ba[c + 3], 0.f);
        uint2 pk;
        pk.x = (uint32)f2bf(v0) | ((uint32)f2bf(v1) << 16);
        pk.y = (uint32)f2bf(v2) | ((uint32)f2bf(v3) << 16);
        *(uint2*)(ob + c) = pk;
    }
}

// ---------------------------------------------------------------------------
// 3x3 conv via MFMA (implicit GEMM over 9 shifted taps).
// inB: [b][ij][CIN] bf16. wB: [kk][64][CIN] bf16. Wave owns 64c x 16ij.
// ---------------------------------------------------------------------------
template <int CIN, int OUT_BF16>
__global__ __launch_bounds__(256) void k_conv3x3M(
    const ushort* __restrict__ inB, const ushort* __restrict__ wB,
    const float* __restrict__ bias, void* __restrict__ outp)
{
    int b = blockIdx.y;
    int wv = threadIdx.x >> 6, l = threadIdx.x & 63;
    int l15 = l & 15, g = l >> 4;
    int tile = blockIdx.x;                 // 0..255
    int i = tile >> 1;
    int j = (tile & 1) * 64 + wv * 16 + l15;
    const ushort* inb = inB + (size_t)b * 16384 * CIN;

    f32x4 acc[4];
#pragma unroll
    for (int m = 0; m < 4; ++m) acc[m] = (f32x4){0.f, 0.f, 0.f, 0.f};

#pragma unroll
    for (int ky = 0; ky < 3; ++ky) {
        int ii = i + ky - 1;
        if (ii < 0 || ii >= 128) continue;      // uniform per block
#pragma unroll
        for (int kx = 0; kx < 3; ++kx) {
            int jv = j + kx - 1;
            bool ok = (jv >= 0) && (jv < 128);  // per-lane
            const ushort* bp = inb + (size_t)(ii * 128 + jv) * CIN + g * 8;
            const ushort* ap = wB + (size_t)((ky * 3 + kx) * 64 + l15) * CIN + g * 8;
#pragma unroll
            for (int o0 = 0; o0 < CIN; o0 += 32) {
                bf16x8 bv;
                if (ok) bv = *(const bf16x8*)(bp + o0);
                else    bv = (bf16x8){0, 0, 0, 0, 0, 0, 0, 0};
#pragma unroll
                for (int m = 0; m < 4; ++m) {
                    bf16x8 av = *(const bf16x8*)(ap + (size_t)(m * 16) * CIN + o0);
                    acc[m] = __builtin_amdgcn_mfma_f32_16x16x32_bf16(av, bv, acc[m], 0, 0, 0);
                }
            }
        }
    }

    int ij = i * 128 + j;
    if (OUT_BF16) {
        ushort* ob = (ushort*)outp + ((size_t)(b * 16384 + ij)) * 64;
#pragma unroll
        for (int m = 0; m < 4; ++m) {
            int c = m * 16 + g * 4;
            float v0 = fmaxf(acc[m][0] + bias[c], 0.f);
            float v1 = fmaxf(acc[m][1] + bias[c + 1], 0.f);
            float v2 = fmaxf(acc[m][2] + bias[c + 2], 0.f);
            float v3 = fmaxf(acc[m][3] + bias[c + 3], 0.f);
            uint2 pk;
            pk.x = (uint32)f2bf(v0) | ((uint32)f2bf(v1) << 16);
            pk.y = (uint32)f2bf(v2) | ((uint32)f2bf(v3) << 16);
            *(uint2*)(ob + c) = pk;
        }
    } else {
        float* of = (float*)outp;
#pragma unroll
        for (int m = 0; m < 4; ++m) {
            int c = m * 16 + g * 4;
#pragma unroll
            for (int r = 0; r < 4; ++r) {
                float v = acc[m][r] + bias[c + r];
                v = v > 0.0f ? v : 0.0f;
                of[((size_t)(b * 64 + c + r)) * 16384 + ij] = v;
            }
        }
    }
}

// ---------------------------------------------------------------------------
// conv-d: 1x1, 64 -> 4, sigmoid, scatter to d_out floats
// ---------------------------------------------------------------------------
__global__ __launch_bounds__(256) void k_convd(
    const float* __restrict__ p3, const float* __restrict__ wd,
    const float* __restrict__ bd, float* __restrict__ outp)
{
    __shared__ float lw[256];
    int b = blockIdx.y;
    int ij = blockIdx.x * 256 + threadIdx.x;
    lw[threadIdx.x] = wd[threadIdx.x];
    __syncthreads();
    float a0 = bd[0], a1 = bd[1], a2 = bd[2], a3 = bd[3];
    for (int c = 0; c < 64; ++c) {
        float v = p3[((size_t)(b * 64 + c)) * 16384 + ij];
        a0 += lw[c] * v;
        a1 += lw[64 + c] * v;
        a2 += lw[128 + c] * v;
        a3 += lw[192 + c] * v;
    }
    outp[1536 + (size_t)(b * 2 + 0) * 16384 + ij] = sigmoidf(a2);  // iou ch0
    outp[1536 + (size_t)(b * 2 + 1) * 16384 + ij] = sigmoidf(a3);  // iou ch1
    outp[132608 + (size_t)b * 16384 + ij] = sigmoidf(a0);          // prop_start
    outp[198144 + (size_t)b * 16384 + ij] = sigmoidf(a1);          // prop_end
}

// ---------------------------------------------------------------------------
extern "C" void kernel_launch(void* const* d_in, const int* in_sizes, int n_in,
                              void* d_out, int out_size, void* d_ws, size_t ws_size,
                              hipStream_t stream)
{
    const float* x   = (const float*)d_in[0];
    const float* w1  = (const float*)d_in[1];
    const float* b1  = (const float*)d_in[2];
    const float* w2  = (const float*)d_in[3];
    const float* b2  = (const float*)d_in[4];
    const float* w3  = (const float*)d_in[5];
    const float* b3  = (const float*)d_in[6];
    const float* w3d = (const float*)d_in[7];
    const float* b3d = (const float*)d_in[8];
    const float* wa  = (const float*)d_in[9];
    const float* ba  = (const float*)d_in[10];
    const float* wb  = (const float*)d_in[11];
    const float* bb  = (const float*)d_in[12];
    const float* wc  = (const float*)d_in[13];
    const float* bc  = (const float*)d_in[14];
    const float* wd  = (const float*)d_in[15];
    const float* bd  = (const float*)d_in[16];
    const float* sm  = (const float*)d_in[17];
    float* outp = (float*)d_out;
    char* ws = (char*)d_ws;

    // workspace layout (with aliasing; peak ~127.3 MB)
    float*  h1    = (float*)(ws + 0);              //  1,048,576 B
    float*  h     = (float*)(ws + 1048576);        //    262,144 B
    ushort* h2t   = (ushort*)(ws + 1310720);       // 16,777,216 B
    uint32* ecnt  = (uint32*)(ws + 18087936);      //  2,097,152 B
    uint8_t* et   = (uint8_t*)(ws + 20185088);     //  4,194,304 B
    float*  ewf   = (float*)(ws + 24379392);       // 16,777,216 B (dead after e2)
    uint32* cntij = (uint32*)(ws + 41156608);      //     65,536 B
    int2*   taps  = (int2*)(ws + 41222144);        // 25,165,824 B
    ushort* cm2   = (ushort*)(ws + 66387968);      // 67,108,864 B  [ij][bo]
    ushort* p1b   = (ushort*)(ws + 1310720);       // 16,777,216 B (aliases h2t; dead then)
    ushort* p2b   = (ushort*)(ws + 41222144);      //  8,388,608 B (aliases taps; dead then)
    float*  p3    = (float*)(ws + 66387968);       // 16,777,216 B (aliases cm2; dead then)
    // transient weight transposes, all inside the ewf zone (24,379,392..41,156,608):
    float*  w1T   = (float*)(ws + 24379392);       //  1,228,800 B (dead before e1)
    float*  w2T   = (float*)(ws + 25608192);       //    786,432 B (dead before e1)
    float*  w3dT  = (float*)(ws + 24379392);       //  8,388,608 B (written after e2)
    ushort* wbB   = (ushort*)(ws + 34865152);      //    147,456 B (written after e2)
    ushort* wcB   = (ushort*)(ws + 35012608);      //     73,728 B
    ushort* waB   = (ushort*)(ws + 35307520);      //    131,072 B (ends < cntij)

    dim3 blk(256);
    k_wtc<<<1200, blk, 0, stream>>>(w1, w1T, 600, 512);
    k_wtc<<<768, blk, 0, stream>>>(w2, w2T, 1536, 128);
    k_conv1d_relu<<<dim3(32, 4), blk, 0, stream>>>(x, w1T, b1, h1, 200, 400, 512);
    k_conv1d_relu<<<dim3(8, 4), blk, 0, stream>>>(h1, w2T, b2, h, 512, 512, 128);
    k_x4<<<1, 512, 0, stream>>>(h, w3, b3, outp);
    k_e1<<<2048, blk, 0, stream>>>(sm, ecnt, et, ewf);
    k_e2<<<8192, 64, 0, stream>>>(ecnt, et, ewf, cntij, taps);
    k_wt5<<<8192, blk, 0, stream>>>(w3d, w3dT);
    k_wt3<<<288, blk, 0, stream>>>(wb, wbB, 128);
    k_wt3<<<144, blk, 0, stream>>>(wc, wcB, 64);
    k_wab<<<256, blk, 0, stream>>>(wa, waB);
    k_h2<<<dim3(8, 32, 4), blk, 0, stream>>>(h, w3dT, h2t);
    k_bm<<<dim3(8, 2048), dim3(64), 0, stream>>>(h2t, taps, cntij, b3d, cm2);
    k_convaM<<<dim3(256, 4), blk, 0, stream>>>(cm2, waB, ba, p1b);
    k_conv3x3M<128, 1><<<dim3(256, 4), blk, 0, stream>>>(p1b, wbB, bb, (void*)p2b);
    k_conv3x3M<64, 0><<<dim3(256, 4), blk, 0, stream>>>(p2b, wcB, bc, (void*)p3);
    k_convd<<<dim3(64, 4), blk, 0, stream>>>(p3, wd, bd, outp);
}

// Round 14
// 817.834 us; speedup vs baseline: 1.4758x; 1.0120x over previous
//
#include <hip/hip_runtime.h>
#include <hip/hip_bf16.h>
#include <stdint.h>

// ---------------------------------------------------------------------------
// Problem geometry
//   x (4,400,128) -> conv1d(200->512,k3,p1,relu) -> conv1d(512->128,k3,p1,relu) = h
//   x4 = sigmoid(0.01*conv1d(h, w3(3,128,1))) -> outputs xc(ch2), xb_start(ch0), xb_end(ch1)
//   cm = einsum('bct,tm->bcm', h, mask) ; conv3d(w3d, stride 32) + b3d, relu
//     == relu(b3d[o] + sum_{s,t} mask[t,s,i,j] * H2[b,o,s,t])   (<=6 taps/(s,i,j))
//   then 1x1(512->128,relu) [MFMA], 3x3(128->64,relu) [MFMA], 3x3(64->64,relu)
//   [MFMA, fused with final 1x1 64->4 sigmoid via cross-lane reduce]
//   outputs (float32): xc,xb_start,xb_end (3*512) | iou (4,2,128,128) | prop_start | prop_end
//
// cm stored TRANSPOSED: cm2[ij][bo]. k_bm: 64-thr single-wave blocks, bo-quad
// per thread, 4 columns interleaved in one loop (4 indep load streams), taps
// broadcast from LDS (zero-padded to cntmax), grid (8 XCD-pinned, 2048).
// MFMA fragment mapping (HW-validated by round-10 conva): A row=lane&15,
// k=(lane>>4)*8+e; B col=lane&15; D col=lane&15, row=(lane>>4)*4+reg.
// ---------------------------------------------------------------------------

typedef unsigned int uint32;
typedef __attribute__((ext_vector_type(8))) short bf16x8;
typedef __attribute__((ext_vector_type(4))) float f32x4;

__device__ __forceinline__ float bf2f(ushort u) {
    return __uint_as_float(((uint32)u) << 16);
}
__device__ __forceinline__ ushort f2bf(float f) {
    uint32 x = __float_as_uint(f);
    uint32 r = (x + 0x7FFFu + ((x >> 16) & 1u)) >> 16;
    return (ushort)r;
}
__device__ __forceinline__ float sigmoidf(float x) {
    return 1.0f / (1.0f + __expf(-x));
}

// ---------------------------------------------------------------------------
// k_wtc: conv1d weights (COUT, CIN, 3) fp32 -> wT[(c*3+k)][COUT] fp32.
// ---------------------------------------------------------------------------
__global__ __launch_bounds__(256) void k_wtc(
    const float* __restrict__ w, float* __restrict__ wT, int CIN3, int COUT)
{
    int n = blockIdx.x * 256 + threadIdx.x;
    if (n >= CIN3 * COUT) return;
    int o = n % COUT, rem = n / COUT;
    wT[n] = w[(size_t)o * CIN3 + rem];
}

// ---------------------------------------------------------------------------
// k_wt5: w3d (512,128,32) fp32 -> w3dT[s][o][c] fp32. Output-indexed.
// ---------------------------------------------------------------------------
__global__ __launch_bounds__(256) void k_wt5(
    const float* __restrict__ w3d, float* __restrict__ w3dT)
{
    int n = blockIdx.x * 256 + threadIdx.x;    // (s*512+o)*128 + c
    int c = n & 127, o = (n >> 7) & 511, s = n >> 16;
    w3dT[n] = w3d[(size_t)o * 4096 + c * 32 + s];
}

// ---------------------------------------------------------------------------
// conv1d (k=3, pad=1, relu). Block: 16 out-channels x 128 t. Grid (COUT/16, B).
// Weights from wT[(c*3+k)][COUT], LDS-staged per 64-channel chunk.
// ---------------------------------------------------------------------------
__global__ __launch_bounds__(256) void k_conv1d_relu(
    const float* __restrict__ in, const float* __restrict__ wT,
    const float* __restrict__ bias, float* __restrict__ out,
    int CIN, int in_batch_stride, int COUT)
{
    __shared__ float lx[64 * 132];   // [c][0..127 data, 128 = zero pad]
    __shared__ float lws[64 * 48];   // [c][k][16 o]
    int b  = blockIdx.y;
    int ooL = threadIdx.x >> 4;
    int o  = blockIdx.x * 16 + ooL;
    int tg = threadIdx.x & 15;
    int t0 = tg * 8;

    float acc[8];
#pragma unroll
    for (int k = 0; k < 8; ++k) acc[k] = 0.0f;

    for (int c0 = 0; c0 < CIN; c0 += 64) {
        int nc = CIN - c0; if (nc > 64) nc = 64;
        __syncthreads();
        for (int n = threadIdx.x; n < nc * 32; n += 256) {
            int cl = n >> 5, q = n & 31;
            float4 v = *(const float4*)(in + ((size_t)(b * in_batch_stride + c0 + cl)) * 128 + q * 4);
            *(float4*)(&lx[cl * 132 + q * 4]) = v;
        }
        for (int cl = threadIdx.x; cl < nc; cl += 256) lx[cl * 132 + 128] = 0.0f;
        for (int n = threadIdx.x; n < nc * 48; n += 256) {
            int cl = n / 48, r = n - cl * 48;       // r = k*16 + oo
            lws[n] = wT[((size_t)(c0 + cl) * 3 + (r >> 4)) * COUT + blockIdx.x * 16 + (r & 15)];
        }
        __syncthreads();

        for (int cl = 0; cl < nc; ++cl) {
            const float* wrow = &lws[cl * 48 + ooL];
            float w0 = wrow[0], w1 = wrow[16], w2 = wrow[32];
            const float* row = &lx[cl * 132];
            float xv[10];
            if (t0 == 0) {
                xv[0] = 0.0f;
#pragma unroll
                for (int k = 1; k < 10; ++k) xv[k] = row[k - 1];
            } else {
#pragma unroll
                for (int k = 0; k < 10; ++k) xv[k] = row[t0 - 1 + k];
            }
#pragma unroll
            for (int k = 0; k < 8; ++k)
                acc[k] += w0 * xv[k] + w1 * xv[k + 1] + w2 * xv[k + 2];
        }
    }
    float bo = bias[o];
#pragma unroll
    for (int k = 0; k < 8; ++k) {
        float v = acc[k] + bo;
        out[((size_t)(b * COUT + o)) * 128 + t0 + k] = v > 0.0f ? v : 0.0f;
    }
}

// ---------------------------------------------------------------------------
// x4 head -> d_out[0:1536] floats: (xc=ch2 | xb_start=ch0 | xb_end=ch1)
// ---------------------------------------------------------------------------
__global__ void k_x4(const float* __restrict__ h, const float* __restrict__ w3,
                     const float* __restrict__ b3, float* __restrict__ outp)
{
    int tid = threadIdx.x;
    int b = tid >> 7, t = tid & 127;
    float a0 = 0.f, a1 = 0.f, a2 = 0.f;
    for (int c = 0; c < 128; ++c) {
        float hv = h[((size_t)(b * 128 + c)) * 128 + t];
        a0 += w3[c] * hv;
        a1 += w3[128 + c] * hv;
        a2 += w3[256 + c] * hv;
    }
    float s0 = sigmoidf(0.01f * (a0 + b3[0]));
    float s1 = sigmoidf(0.01f * (a1 + b3[1]));
    float s2 = sigmoidf(0.01f * (a2 + b3[2]));
    int bt = b * 128 + t;
    outp[bt]        = s2;   // xc
    outp[512 + bt]  = s0;   // xb_start
    outp[1024 + bt] = s1;   // xb_end
}

// ---------------------------------------------------------------------------
// H2t[(s*128+t)*2048 + b*512+o] = bf16( sum_c w3dT[s][o][c]*h[b,c,t] )
// ---------------------------------------------------------------------------
__global__ __launch_bounds__(256) void k_h2(
    const float* __restrict__ h, const float* __restrict__ w3dT,
    ushort* __restrict__ h2t)
{
    __shared__ float lw[64 * 132];     // [o][c] stride 132
    __shared__ float lhs[32 * 132];    // [c_local][t] ; reused as out stage
    int ot = blockIdx.x, s = blockIdx.y, b = blockIdx.z;
    int o0 = ot * 64;

    for (int n = threadIdx.x; n < 2048; n += 256) {
        int o = n >> 5, q = n & 31;
        *(float4*)(&lw[o * 132 + q * 4]) =
            *(const float4*)(w3dT + ((size_t)(s * 512 + o0 + o)) * 128 + q * 4);
    }

    int og = threadIdx.x >> 4, tg = threadIdx.x & 15;
    int o0t = og * 4, t0 = tg * 8;
    float acc[4][8];
#pragma unroll
    for (int oo = 0; oo < 4; ++oo)
#pragma unroll
        for (int k = 0; k < 8; ++k) acc[oo][k] = 0.0f;

    for (int c0 = 0; c0 < 128; c0 += 32) {
        __syncthreads();
        for (int n = threadIdx.x; n < 1024; n += 256) {
            int cl = n >> 5, q = n & 31;
            *(float4*)(&lhs[cl * 132 + q * 4]) =
                *(const float4*)(h + ((size_t)(b * 128 + c0 + cl)) * 128 + q * 4);
        }
        __syncthreads();
        for (int cl = 0; cl < 32; ++cl) {
            float hv[8];
#pragma unroll
            for (int k = 0; k < 8; ++k) hv[k] = lhs[cl * 132 + t0 + k];
#pragma unroll
            for (int oo = 0; oo < 4; ++oo) {
                float wv = lw[(o0t + oo) * 132 + c0 + cl];
#pragma unroll
                for (int k = 0; k < 8; ++k) acc[oo][k] += wv * hv[k];
            }
        }
    }
    __syncthreads();
    ushort* lout = (ushort*)lhs;       // [t*64 + o]
#pragma unroll
    for (int oo = 0; oo < 4; ++oo)
#pragma unroll
        for (int k = 0; k < 8; ++k)
            lout[(t0 + k) * 64 + o0t + oo] = f2bf(acc[oo][k]);
    __syncthreads();
    for (int n = threadIdx.x; n < 8192; n += 256) {
        int t = n >> 6, o = n & 63;
        h2t[(size_t)(s * 128 + t) * 2048 + b * 512 + o0 + o] = lout[n];
    }
}

// ---------------------------------------------------------------------------
// E1: per mask column m=(s,i,j), collect nonzero (t,w) taps (<=6 exist, cap 8).
// ---------------------------------------------------------------------------
__global__ __launch_bounds__(256) void k_e1(
    const float* __restrict__ mask, uint32* __restrict__ ecnt,
    uint8_t* __restrict__ et, float* __restrict__ ew)
{
    uint32 m = blockIdx.x * 256 + threadIdx.x;
    int cnt = 0;
    for (int t = 0; t < 128; ++t) {
        float w = mask[(size_t)t * 524288 + m];
        if (w != 0.0f) {
            if (cnt < 8) {
                et[(size_t)m * 8 + cnt] = (uint8_t)t;
                ew[(size_t)m * 8 + cnt] = w;
            }
            cnt++;
        }
    }
    ecnt[m] = (uint32)(cnt < 8 ? cnt : 8);
}

// ---------------------------------------------------------------------------
// E2: merge per (i,j): taps over all 32 s -> packed {w_bits, byte_off} (<=192).
// ---------------------------------------------------------------------------
__global__ void k_e2(const uint32* __restrict__ ecnt, const uint8_t* __restrict__ et,
                     const float* __restrict__ ew, uint32* __restrict__ cntij,
                     int2* __restrict__ taps)
{
    int lane = threadIdx.x & 31;
    int col = blockIdx.x * 2 + (threadIdx.x >> 5);
    uint32 m = (uint32)lane * 16384u + (uint32)col;
    int c = (int)ecnt[m];
    int v = c;
    for (int d = 1; d < 32; d <<= 1) {
        int t = __shfl_up(v, d, 32);
        if (lane >= d) v += t;
    }
    int off = v - c;
    if (lane == 31) cntij[col] = (uint32)v;
    for (int k = 0; k < c; ++k) {
        int2 r;
        r.x = __float_as_int(ew[(size_t)m * 8 + k]);
        r.y = ((lane << 7) + (int)et[(size_t)m * 8 + k]) << 12;   // st * 4096 bytes
        taps[(size_t)col * 192 + off + k] = r;
    }
}

// ---------------------------------------------------------------------------
// k_wt3: conv3x3 weights (64, CIN, 3, 3) fp32 -> bf16 [kk][cout][cin]
// ---------------------------------------------------------------------------
__global__ __launch_bounds__(256) void k_wt3(
    const float* __restrict__ w, ushort* __restrict__ wB, int CIN)
{
    int n = blockIdx.x * 256 + threadIdx.x;
    int total = 64 * CIN * 9;
    if (n >= total) return;
    int kk = n % 9;
    int rest = n / 9;                  // cout*CIN + cin
    int cin = rest & (CIN - 1);
    int cout = rest / CIN;
    wB[((size_t)(kk * 64 + cout)) * CIN + cin] = f2bf(w[n]);
}

// ---------------------------------------------------------------------------
// k_wab: cast wa (128x512 fp32) -> bf16, same row-major layout.
// ---------------------------------------------------------------------------
__global__ __launch_bounds__(256) void k_wab(
    const float* __restrict__ wa, ushort* __restrict__ waB)
{
    int n = blockIdx.x * 256 + threadIdx.x;   // 65536 total
    waB[n] = f2bf(wa[n]);
}

// ---------------------------------------------------------------------------
// k_bm: cm2[ij, bo] = relu(b3d[o] + sum_taps w * H2t[st, bo])   (bf16 out)
// 64-thr single-wave blocks; bo-quad per thread (dwordx2 = 4 bf16 = 4 MACs).
// The 4 staged columns are interleaved in ONE k-loop (4 independent load
// streams per wave for latency hiding); LDS padding beyond cnt[c] is zeroed
// so extra iterations are exact no-ops. Grid (x=boT 8 -> XCD-pinned 2MB h2t
// slice, y = i*16 + oct8) = 16384 blocks.
// ---------------------------------------------------------------------------
__global__ __launch_bounds__(64) void k_bm(
    const ushort* __restrict__ h2t, const int2* __restrict__ taps,
    const uint32* __restrict__ cntij, const float* __restrict__ b3d,
    ushort* __restrict__ cm2)
{
    __shared__ int2 tl[4 * 192];        // 6,144 B
    int boT = blockIdx.x;
    int i = blockIdx.y >> 4, oc = blockIdx.y & 15;
    int tid = threadIdx.x;
    int bo0 = boT * 256 + tid * 4;
    const char* hb = (const char*)h2t + (size_t)bo0 * 2;
    float4 bias = *(const float4*)(b3d + (bo0 & 511));

    for (int jc = 0; jc < 2; ++jc) {
        int j0 = oc * 8 + jc * 4;
        int ij0 = i * 128 + j0;
        int cnts[4];
#pragma unroll
        for (int c = 0; c < 4; ++c) cnts[c] = (int)cntij[ij0 + c];
        int cntmax = cnts[0];
#pragma unroll
        for (int c = 1; c < 4; ++c) cntmax = cnts[c] > cntmax ? cnts[c] : cntmax;
        __syncthreads();   // previous chunk's readers done before tl overwrite
        for (int n = tid; n < 768; n += 64) {
            int c = n / 192, k = n - c * 192;
            int2 v = {0, 0};
            if (k < cnts[c]) v = taps[(size_t)(ij0 + c) * 192 + k];
            tl[n] = v;
        }
        __syncthreads();

        float a[4][4];
#pragma unroll
        for (int c = 0; c < 4; ++c)
#pragma unroll
            for (int r = 0; r < 4; ++r) a[c][r] = 0.0f;

#pragma unroll 2
        for (int k = 0; k < cntmax; ++k) {
#pragma unroll
            for (int c = 0; c < 4; ++c) {
                int2 r = tl[c * 192 + k];
                uint2 hv = *(const uint2*)(hb + (uint32)r.y);
                float w = __int_as_float(r.x);
                a[c][0] += w * __uint_as_float(hv.x << 16);
                a[c][1] += w * __uint_as_float(hv.x & 0xffff0000u);
                a[c][2] += w * __uint_as_float(hv.y << 16);
                a[c][3] += w * __uint_as_float(hv.y & 0xffff0000u);
            }
        }
#pragma unroll
        for (int c = 0; c < 4; ++c) {
            float v0 = fmaxf(a[c][0] + bias.x, 0.f);
            float v1 = fmaxf(a[c][1] + bias.y, 0.f);
            float v2 = fmaxf(a[c][2] + bias.z, 0.f);
            float v3 = fmaxf(a[c][3] + bias.w, 0.f);
            uint64_t pr = (uint64_t)((uint32)f2bf(v0) | ((uint32)f2bf(v1) << 16))
                        | ((uint64_t)((uint32)f2bf(v2) | ((uint32)f2bf(v3) << 16)) << 32);
            __builtin_nontemporal_store(pr, (uint64_t*)(cm2 + (size_t)(ij0 + c) * 2048 + bo0));
        }
    }
}

// ---------------------------------------------------------------------------
// conv-a via MFMA: p1b[b][ij][c] = bf16(relu(ba[c] + sum_o waB[c,o]*cm2[ij,b*512+o]))
// ---------------------------------------------------------------------------
__global__ __launch_bounds__(256) void k_convaM(
    const ushort* __restrict__ cm2, const ushort* __restrict__ waB,
    const float* __restrict__ ba, ushort* __restrict__ p1b)
{
    int b = blockIdx.y;
    int wv = threadIdx.x >> 6, l = threadIdx.x & 63;
    int ij0 = blockIdx.x * 64 + wv * 16;
    int l15 = l & 15, g = l >> 4;

    f32x4 acc[8];
#pragma unroll
    for (int m = 0; m < 8; ++m) acc[m] = (f32x4){0.f, 0.f, 0.f, 0.f};

    const ushort* bbase = cm2 + (size_t)(ij0 + l15) * 2048 + b * 512 + g * 8;
    const ushort* abase = waB + (size_t)l15 * 512 + g * 8;

#pragma unroll 2
    for (int o0 = 0; o0 < 512; o0 += 32) {
        bf16x8 bv = *(const bf16x8*)(bbase + o0);
#pragma unroll
        for (int m = 0; m < 8; ++m) {
            bf16x8 av = *(const bf16x8*)(abase + (size_t)(m * 16) * 512 + o0);
            acc[m] = __builtin_amdgcn_mfma_f32_16x16x32_bf16(av, bv, acc[m], 0, 0, 0);
        }
    }

    int ij = ij0 + l15;
    ushort* ob = p1b + ((size_t)(b * 16384 + ij)) * 128;
#pragma unroll
    for (int m = 0; m < 8; ++m) {
        int c = m * 16 + g * 4;
        float v0 = fmaxf(acc[m][0] + ba[c], 0.f);
        float v1 = fmaxf(acc[m][1] + ba[c + 1], 0.f);
        float v2 = fmaxf(acc[m][2] + ba[c + 2], 0.f);
        float v3 = fmaxf(acc[m][3] + ba[c + 3], 0.f);
        uint2 pk;
        pk.x = (uint32)f2bf(v0) | ((uint32)f2bf(v1) << 16);
        pk.y = (uint32)f2bf(v2) | ((uint32)f2bf(v3) << 16);
        *(uint2*)(ob + c) = pk;
    }
}

// ---------------------------------------------------------------------------
// 3x3 conv via MFMA (implicit GEMM over 9 shifted taps).
// inB: [b][ij][CIN] bf16. wB: [kk][64][CIN] bf16. Wave owns 64c x 16ij.
// MODE 1: bf16 out [b][ij][64]. MODE 2: fused final 1x1(64->4)+sigmoid:
// cross-lane (g) reduce of wd-dot-products, lanes g==0 store to d_out.
// ---------------------------------------------------------------------------
template <int CIN, int MODE>
__global__ __launch_bounds__(256) void k_conv3x3M(
    const ushort* __restrict__ inB, const ushort* __restrict__ wB,
    const float* __restrict__ bias, void* __restrict__ outp,
    const float* __restrict__ wd, const float* __restrict__ bd)
{
    int b = blockIdx.y;
    int wv = threadIdx.x >> 6, l = threadIdx.x & 63;
    int l15 = l & 15, g = l >> 4;
    int tile = blockIdx.x;                 // 0..255
    int i = tile >> 1;
    int j = (tile & 1) * 64 + wv * 16 + l15;
    const ushort* inb = inB + (size_t)b * 16384 * CIN;

    f32x4 acc[4];
#pragma unroll
    for (int m = 0; m < 4; ++m) acc[m] = (f32x4){0.f, 0.f, 0.f, 0.f};

#pragma unroll
    for (int ky = 0; ky < 3; ++ky) {
        int ii = i + ky - 1;
        if (ii < 0 || ii >= 128) continue;      // uniform per block
#pragma unroll
        for (int kx = 0; kx < 3; ++kx) {
            int jv = j + kx - 1;
            bool ok = (jv >= 0) && (jv < 128);  // per-lane
            const ushort* bp = inb + (size_t)(ii * 128 + jv) * CIN + g * 8;
            const ushort* ap = wB + (size_t)((ky * 3 + kx) * 64 + l15) * CIN + g * 8;
#pragma unroll
            for (int o0 = 0; o0 < CIN; o0 += 32) {
                bf16x8 bv;
                if (ok) bv = *(const bf16x8*)(bp + o0);
                else    bv = (bf16x8){0, 0, 0, 0, 0, 0, 0, 0};
#pragma unroll
                for (int m = 0; m < 4; ++m) {
                    bf16x8 av = *(const bf16x8*)(ap + (size_t)(m * 16) * CIN + o0);
                    acc[m] = __builtin_amdgcn_mfma_f32_16x16x32_bf16(av, bv, acc[m], 0, 0, 0);
                }
            }
        }
    }

    int ij = i * 128 + j;
    if (MODE == 1) {
        ushort* ob = (ushort*)outp + ((size_t)(b * 16384 + ij)) * 64;
#pragma unroll
        for (int m = 0; m < 4; ++m) {
            int c = m * 16 + g * 4;
            float v0 = fmaxf(acc[m][0] + bias[c], 0.f);
            float v1 = fmaxf(acc[m][1] + bias[c + 1], 0.f);
            float v2 = fmaxf(acc[m][2] + bias[c + 2], 0.f);
            float v3 = fmaxf(acc[m][3] + bias[c + 3], 0.f);
            uint2 pk;
            pk.x = (uint32)f2bf(v0) | ((uint32)f2bf(v1) << 16);
            pk.y = (uint32)f2bf(v2) | ((uint32)f2bf(v3) << 16);
            *(uint2*)(ob + c) = pk;
        }
    } else {
        // MODE 2: relu(conv_c) then fused 1x1(64->4) + sigmoid to d_out.
        float v[4][4];
#pragma unroll
        for (int m = 0; m < 4; ++m) {
            int c = m * 16 + g * 4;
#pragma unroll
            for (int r = 0; r < 4; ++r)
                v[m][r] = fmaxf(acc[m][r] + bias[c + r], 0.f);
        }
        float s[4];
#pragma unroll
        for (int oc = 0; oc < 4; ++oc) {
            float t = 0.0f;
#pragma unroll
            for (int m = 0; m < 4; ++m) {
                int c = m * 16 + g * 4;
#pragma unroll
                for (int r = 0; r < 4; ++r)
                    t += wd[oc * 64 + c + r] * v[m][r];
            }
            t += __shfl_xor(t, 16);
            t += __shfl_xor(t, 32);
            s[oc] = t;
        }
        if (g == 0) {
            float* od = (float*)outp;
            od[1536 + (size_t)(b * 2 + 0) * 16384 + ij] = sigmoidf(s[2] + bd[2]);  // iou ch0
            od[1536 + (size_t)(b * 2 + 1) * 16384 + ij] = sigmoidf(s[3] + bd[3]);  // iou ch1
            od[132608 + (size_t)b * 16384 + ij] = sigmoidf(s[0] + bd[0]);          // prop_start
            od[198144 + (size_t)b * 16384 + ij] = sigmoidf(s[1] + bd[1]);          // prop_end
        }
    }
}

// ---------------------------------------------------------------------------
extern "C" void kernel_launch(void* const* d_in, const int* in_sizes, int n_in,
                              void* d_out, int out_size, void* d_ws, size_t ws_size,
                              hipStream_t stream)
{
    const float* x   = (const float*)d_in[0];
    const float* w1  = (const float*)d_in[1];
    const float* b1  = (const float*)d_in[2];
    const float* w2  = (const float*)d_in[3];
    const float* b2  = (const float*)d_in[4];
    const float* w3  = (const float*)d_in[5];
    const float* b3  = (const float*)d_in[6];
    const float* w3d = (const float*)d_in[7];
    const float* b3d = (const float*)d_in[8];
    const float* wa  = (const float*)d_in[9];
    const float* ba  = (const float*)d_in[10];
    const float* wb  = (const float*)d_in[11];
    const float* bb  = (const float*)d_in[12];
    const float* wc  = (const float*)d_in[13];
    const float* bc  = (const float*)d_in[14];
    const float* wd  = (const float*)d_in[15];
    const float* bd  = (const float*)d_in[16];
    const float* sm  = (const float*)d_in[17];
    float* outp = (float*)d_out;
    char* ws = (char*)d_ws;

    // workspace layout (with aliasing; peak ~127.3 MB)
    float*  h1    = (float*)(ws + 0);              //  1,048,576 B
    float*  h     = (float*)(ws + 1048576);        //    262,144 B
    ushort* h2t   = (ushort*)(ws + 1310720);       // 16,777,216 B
    uint32* ecnt  = (uint32*)(ws + 18087936);      //  2,097,152 B
    uint8_t* et   = (uint8_t*)(ws + 20185088);     //  4,194,304 B
    float*  ewf   = (float*)(ws + 24379392);       // 16,777,216 B (dead after e2)
    uint32* cntij = (uint32*)(ws + 41156608);      //     65,536 B
    int2*   taps  = (int2*)(ws + 41222144);        // 25,165,824 B
    ushort* cm2   = (ushort*)(ws + 66387968);      // 67,108,864 B  [ij][bo]
    ushort* p1b   = (ushort*)(ws + 1310720);       // 16,777,216 B (aliases h2t; dead then)
    ushort* p2b   = (ushort*)(ws + 41222144);      //  8,388,608 B (aliases taps; dead then)
    // transient weight transposes, all inside the ewf zone (24,379,392..41,156,608):
    float*  w1T   = (float*)(ws + 24379392);       //  1,228,800 B (dead before e1)
    float*  w2T   = (float*)(ws + 25608192);       //    786,432 B (dead before e1)
    float*  w3dT  = (float*)(ws + 24379392);       //  8,388,608 B (written after e2)
    ushort* wbB   = (ushort*)(ws + 34865152);      //    147,456 B (written after e2)
    ushort* wcB   = (ushort*)(ws + 35012608);      //     73,728 B
    ushort* waB   = (ushort*)(ws + 35307520);      //    131,072 B (ends < cntij)

    dim3 blk(256);
    k_wtc<<<1200, blk, 0, stream>>>(w1, w1T, 600, 512);
    k_wtc<<<768, blk, 0, stream>>>(w2, w2T, 1536, 128);
    k_conv1d_relu<<<dim3(32, 4), blk, 0, stream>>>(x, w1T, b1, h1, 200, 400, 512);
    k_conv1d_relu<<<dim3(8, 4), blk, 0, stream>>>(h1, w2T, b2, h, 512, 512, 128);
    k_x4<<<1, 512, 0, stream>>>(h, w3, b3, outp);
    k_e1<<<2048, blk, 0, stream>>>(sm, ecnt, et, ewf);
    k_e2<<<8192, 64, 0, stream>>>(ecnt, et, ewf, cntij, taps);
    k_wt5<<<8192, blk, 0, stream>>>(w3d, w3dT);
    k_wt3<<<288, blk, 0, stream>>>(wb, wbB, 128);
    k_wt3<<<144, blk, 0, stream>>>(wc, wcB, 64);
    k_wab<<<256, blk, 0, stream>>>(wa, waB);
    k_h2<<<dim3(8, 32, 4), blk, 0, stream>>>(h, w3dT, h2t);
    k_bm<<<dim3(8, 2048), dim3(64), 0, stream>>>(h2t, taps, cntij, b3d, cm2);
    k_convaM<<<dim3(256, 4), blk, 0, stream>>>(cm2, waB, ba, p1b);
    k_conv3x3M<128, 1><<<dim3(256, 4), blk, 0, stream>>>(p1b, wbB, bb, (void*)p2b, nullptr, nullptr);
    k_conv3x3M<64, 2><<<dim3(256, 4), blk, 0, stream>>>(p2b, wcB, bc, (void*)outp, wd, bd);
}